// Round 2
// baseline (644.905 us; speedup 1.0000x reference)
//
#include <hip/hip_runtime.h>
#include <math.h>

#define NN 50000
#define NPAD 50048
#define EE 800000
#define HIDC 256
#define INCH 320

typedef __attribute__((ext_vector_type(8))) short bf16x8;
typedef __attribute__((ext_vector_type(4))) float f32x4;
typedef __attribute__((ext_vector_type(2))) float f32x2;

static __device__ __forceinline__ float4 ld4(const float* p){ return *(const float4*)p; }

static __device__ __forceinline__ unsigned short f2b(float f){
  union { float f; unsigned u; } v; v.f = f;
  unsigned r = v.u + 0x7fffu + ((v.u >> 16) & 1u);
  return (unsigned short)(r >> 16);
}
static __device__ __forceinline__ float b2f(unsigned short u){
  union { unsigned u; float f; } v; v.u = ((unsigned)u) << 16; return v.f;
}
// unpack two bf16 packed in a u32 -> 2 floats (lo = .x, hi = .y)
static __device__ __forceinline__ f32x2 unpk(unsigned u){
  f32x2 r;
  r.x = __uint_as_float(u << 16);
  r.y = __uint_as_float(u & 0xffff0000u);
  return r;
}
static __device__ __forceinline__ f32x2 fma2(f32x2 a, f32x2 b, f32x2 c){
  return __builtin_elementwise_fma(a, b, c);
}
static __device__ __forceinline__ f32x2 max2(f32x2 a, f32x2 b){
  return __builtin_elementwise_max(a, b);
}
static __device__ __forceinline__ f32x2 set2(float v){ f32x2 r; r.x = v; r.y = v; return r; }

typedef const __attribute__((address_space(1))) unsigned int* gas_u32;
typedef __attribute__((address_space(3))) unsigned int* las_u32;
static __device__ __forceinline__ void gload_lds16(const void* g, void* l){
  __builtin_amdgcn_global_load_lds((gas_u32)g, (las_u32)l, 16, 0, 0);
}

// ---------------- convert x (fp32 50000x256) into node_x bf16 (NPAD x 320, cols 0..255) ----------------
__global__ void cvt_x_kernel(const float* __restrict__ x, unsigned short* __restrict__ nodex)
{
  int t = blockIdx.x*blockDim.x + threadIdx.x;
  int row = t >> 6;
  if (row >= NN) return;
  int c4 = (t & 63) * 4;
  float4 v = ld4(x + (size_t)row*256 + c4);
  ushort4 o;
  o.x = f2b(v.x); o.y = f2b(v.y); o.z = f2b(v.z); o.w = f2b(v.w);
  *(ushort4*)(nodex + (size_t)row*320 + c4) = o;
}

// ---------------- node positional MLP: writes bf16 into node_x cols 256..319 ----------------
__global__ void node_mlp_kernel(const float* __restrict__ kpts,
                                const float* __restrict__ pts3d,
                                const float* __restrict__ W1, const float* __restrict__ b1,
                                const float* __restrict__ W2, const float* __restrict__ b2,
                                unsigned short* __restrict__ nodex)
{
  int i = blockIdx.x*blockDim.x + threadIdx.x;
  if (i >= NN) return;
  float u = kpts[2*i]   * (1.0f/1216.0f);
  float v = kpts[2*i+1] * (1.0f/352.0f);
  float d = pts3d[3*i+2];
  float h[32];
#pragma unroll
  for (int j=0;j<32;++j){
    float t = u*W1[j] + v*W1[32+j] + d*W1[64+j] + b1[j];
    h[j] = t / (1.0f + __expf(-t));   // silu
  }
  for (int o=0;o<64;o+=4){
    float s0=b2[o], s1=b2[o+1], s2=b2[o+2], s3=b2[o+3];
#pragma unroll
    for (int j=0;j<32;++j){
      float hj = h[j];
      const float* w = W2 + j*64 + o;
      s0 += hj*w[0]; s1 += hj*w[1]; s2 += hj*w[2]; s3 += hj*w[3];
    }
    ushort4 r; r.x=f2b(s0); r.y=f2b(s1); r.z=f2b(s2); r.w=f2b(s3);
    *(ushort4*)(nodex + (size_t)i*320 + 256 + o) = r;
  }
}

// ---------------- convert + transpose weights to bf16 N-major (K contiguous) + bias concat ----------------
__global__ void cvt_w_kernel(const float* __restrict__ Wres, const float* __restrict__ Wl,
                             const float* __restrict__ Wr,   const float* __restrict__ Wp,
                             const float* __restrict__ bres, const float* __restrict__ bl,
                             const float* __restrict__ br,
                             unsigned short* __restrict__ wt, float* __restrict__ biascat)
{
  int t = blockIdx.x*blockDim.x + threadIdx.x;   // 312064 threads
  if (t < 245760) {
    int which = t / 81920;
    int rem = t % 81920;
    int n = rem / 320, k = rem % 320;
    const float* W = (which == 0) ? Wres : (which == 1) ? Wl : Wr;
    wt[(size_t)which*81920 + rem] = f2b(W[(size_t)k*256 + n]);
  } else if (t < 311296) {
    int r = t - 245760;
    int n = r / 256, k = r % 256;
    wt[245760 + r] = f2b(Wp[(size_t)k*256 + n]);
  } else {
    int r = t - 311296;   // 0..767
    const float* src = (r < 256) ? bres : (r < 512) ? bl : br;
    biascat[r] = src[r & 255];
  }
}

// ---------------- bf16 MFMA GEMM: C(M,Nt) = A(M,K) @ BT(Nt,K)^T + bias ----------------
#define GK 32
__global__ __launch_bounds__(256) void mfma_gemm_kernel(
    const unsigned short* __restrict__ A,
    const unsigned short* __restrict__ BT,
    const float* __restrict__ bias,
    float* __restrict__ Cf,
    unsigned short* __restrict__ Cx1,
    unsigned short* __restrict__ Cx2,
    int M, int K)
{
  __shared__ unsigned short Als[128*GK];
  __shared__ unsigned short Bls[128*GK];
  int tid = threadIdx.x;
  int lane = tid & 63, wave = tid >> 6;
  int wm = (wave >> 1) * 64, wn = (wave & 1) * 64;
  int row0 = blockIdx.x * 128, col0 = blockIdx.y * 128;

  f32x4 acc[4][4];
#pragma unroll
  for (int i=0;i<4;++i)
#pragma unroll
    for (int j=0;j<4;++j){ acc[i][j].x=0.f; acc[i][j].y=0.f; acc[i][j].z=0.f; acc[i][j].w=0.f; }

  int fm = lane & 15;
  int fk = (lane >> 4) * 8;

  for (int k0 = 0; k0 < K; k0 += GK) {
#pragma unroll
    for (int it = 0; it < 2; ++it) {
      int seg = it*256 + tid;
      int r = seg >> 2, kb = (seg & 3) * 8;
      gload_lds16(A  + (size_t)(row0 + r)*K + k0 + kb, Als + (it*256 + wave*64)*8);
      gload_lds16(BT + (size_t)(col0 + r)*K + k0 + kb, Bls + (it*256 + wave*64)*8);
    }
    __syncthreads();

    bf16x8 af[4], bfr[4];
#pragma unroll
    for (int mi=0; mi<4; ++mi)
      af[mi] = *(const bf16x8*)&Als[(wm + mi*16 + fm)*GK + fk];
#pragma unroll
    for (int ni=0; ni<4; ++ni)
      bfr[ni] = *(const bf16x8*)&Bls[(wn + ni*16 + fm)*GK + fk];
#pragma unroll
    for (int mi=0; mi<4; ++mi)
#pragma unroll
      for (int ni=0; ni<4; ++ni)
        acc[mi][ni] = __builtin_amdgcn_mfma_f32_16x16x32_bf16(af[mi], bfr[ni], acc[mi][ni], 0, 0, 0);
    __syncthreads();
  }

  int seg = col0 >> 8;
  int colbase = col0 - seg*256;
  int cn = lane & 15, cr = (lane >> 4) * 4;
#pragma unroll
  for (int ni=0; ni<4; ++ni){
    int gcol = col0 + wn + ni*16 + cn;
    int col  = colbase + wn + ni*16 + cn;
    float bb = bias[gcol];
#pragma unroll
    for (int mi=0; mi<4; ++mi){
#pragma unroll
      for (int r=0; r<4; ++r){
        int row = row0 + wm + mi*16 + cr + r;
        if (row < M){
          float v = acc[mi][ni][r] + bb;
          if (seg == 0)      Cf [(size_t)row*256 + col] = v;
          else if (seg == 1) Cx1[(size_t)row*256 + col] = f2b(v);
          else               Cx2[(size_t)row*256 + col] = f2b(v);
        }
      }
    }
  }
}

// ---------------- CSR build by dst ----------------
__global__ void hist_kernel(const int* __restrict__ ei, int* __restrict__ deg){
  int e = blockIdx.x*blockDim.x + threadIdx.x;
  if (e < EE) atomicAdd(&deg[ei[EE + e]], 1);
}

// parallel 3-phase scan
__global__ __launch_bounds__(1024) void scan1_kernel(const int* __restrict__ deg,
                                                     int* __restrict__ incl, int* __restrict__ bsum){
  __shared__ int wsums[16];
  int t = threadIdx.x, lane = t & 63, w = t >> 6;
  int i = blockIdx.x*1024 + t;
  int v = (i < NN) ? deg[i] : 0;
  int sc = v;
#pragma unroll
  for (int off = 1; off < 64; off <<= 1) {
    int o = __shfl_up(sc, off, 64);
    if (lane >= off) sc += o;
  }
  if (lane == 63) wsums[w] = sc;
  __syncthreads();
  if (w == 0) {
    int ws = (lane < 16) ? wsums[lane] : 0;
#pragma unroll
    for (int off = 1; off < 16; off <<= 1) {
      int o = __shfl_up(ws, off, 64);
      if (lane >= off) ws += o;
    }
    if (lane < 16) wsums[lane] = ws;
  }
  __syncthreads();
  int woff = (w > 0) ? wsums[w-1] : 0;
  if (i < NN) incl[i] = sc + woff;
  if (t == 1023) bsum[blockIdx.x] = woff + sc;
}

__global__ void scan2_kernel(int* __restrict__ bsum, int nblk){
  int lane = threadIdx.x;
  int v = (lane < nblk) ? bsum[lane] : 0;
#pragma unroll
  for (int off = 1; off < 64; off <<= 1) {
    int o = __shfl_up(v, off, 64);
    if (lane >= off) v += o;
  }
  if (lane < nblk) bsum[lane] = v;
}

__global__ __launch_bounds__(1024) void scan3_kernel(const int* __restrict__ incl,
                                                     const int* __restrict__ deg,
                                                     const int* __restrict__ bsum,
                                                     int* __restrict__ rowptr, int* __restrict__ cursor,
                                                     int nblk){
  int i = blockIdx.x*1024 + threadIdx.x;
  if (i < NN) {
    int b = blockIdx.x;
    int prev = (b > 0) ? bsum[b-1] : 0;
    int ex = prev + incl[i] - deg[i];
    rowptr[i] = ex;
    cursor[i] = ex;
  }
  if (i == 0) rowptr[NN] = bsum[nblk-1];
}

// scatter: place edge into its dst bin AND precompute edge geometry
__global__ void scatter_kernel(const int* __restrict__ ei, const float* __restrict__ kpts,
                               int* __restrict__ cursor,
                               float4* __restrict__ edata, int* __restrict__ eord){
  int e = blockIdx.x*blockDim.x + threadIdx.x;
  if (e >= EE) return;
  int s = ei[e];
  int d = ei[EE + e];
  int pos = atomicAdd(&cursor[d], 1);
  float su = kpts[2*s]   * (1.0f/1216.0f);
  float sv = kpts[2*s+1] * (1.0f/352.0f);
  float du = kpts[2*d]   * (1.0f/1216.0f);
  float dv = kpts[2*d+1] * (1.0f/352.0f);
  float ru = du - su, rv = dv - sv;
  float dist = sqrtf(ru*ru + rv*rv);
  float4 ed; ed.x = ru; ed.y = rv; ed.z = dist; ed.w = __int_as_float(s);
  edata[pos] = ed;
  eord[pos] = e;
}

// ---------------- per-node attention ----------------
// 1 wave per node; two 32-lane halves each own one edge per pair-slot
// (2 edges concurrent). Lane covers 8 channels (c0=(lane&31)*8), one head.
// Depth-4 ping-pong pipeline: while group A (4 pairs) is processed, group B's
// 4 edata loads + 4 dependent xl gathers are in flight (8 outstanding VMEM/wave,
// matching the original kernel's LOAD8 depth). 4 statically-unrolled PROC
// chains interleave their shfl/exp dependency chains for ILP.

#define LOAD_ED(P, ED)                                               \
  {                                                                  \
    int j_ = 2*(P) + half;                                           \
    int idx_ = rs + ((j_ < deg) ? j_ : 0);                           \
    ED = edata[idx_];                                                \
  }

#define LOAD_Q(ED, Q)                                                \
  {                                                                  \
    int s_ = __float_as_int((ED).w);                                 \
    Q = *(const uint4*)(xlp + ((size_t)s_ << 8));                    \
  }

#define PROC_E(P, ED, Q)                                             \
  {                                                                  \
    int jj_ = 2*(P) + half;                                          \
    bool act = jj_ < deg;                                            \
    f32x2 x0 = unpk((Q).x), x1 = unpk((Q).y);                        \
    f32x2 x2 = unpk((Q).z), x3 = unpk((Q).w);                        \
    f32x2 ru = set2((ED).x), rv = set2((ED).y), dd = set2((ED).z);   \
    f32x2 t0 = fma2(ru, w0[0], xr4[0]);                              \
    f32x2 t1 = fma2(ru, w0[1], xr4[1]);                              \
    f32x2 t2 = fma2(ru, w0[2], xr4[2]);                              \
    f32x2 t3 = fma2(ru, w0[3], xr4[3]);                              \
    t0 = fma2(rv, w1[0], t0); t1 = fma2(rv, w1[1], t1);              \
    t2 = fma2(rv, w1[2], t2); t3 = fma2(rv, w1[3], t3);              \
    t0 = fma2(dd, w2[0], t0); t1 = fma2(dd, w2[1], t1);              \
    t2 = fma2(dd, w2[2], t2); t3 = fma2(dd, w2[3], t3);              \
    t0 = t0 + x0; t1 = t1 + x1; t2 = t2 + x2; t3 = t3 + x3;          \
    t0 = max2(t0, t0*0.2f); t1 = max2(t1, t1*0.2f);                  \
    t2 = max2(t2, t2*0.2f); t3 = max2(t3, t3*0.2f);                  \
    f32x2 pd = t0*at4[0];                                            \
    pd = fma2(t1, at4[1], pd);                                       \
    pd = fma2(t2, at4[2], pd);                                       \
    pd = fma2(t3, at4[3], pd);                                       \
    float p = pd.x + pd.y;                                           \
    p += __shfl_xor(p, 1, 64);                                       \
    p += __shfl_xor(p, 2, 64);                                       \
    p += __shfl_xor(p, 4, 64);                                       \
    float exv = act ? __expf(p) : 0.0f;                              \
    denom += exv;                                                    \
    if (act && (li & 7) == 0)                                        \
      alpha_out[(size_t)eop[jj_]*4 + head] = exv;                    \
    f32x2 ex2 = set2(exv);                                           \
    agg[0] = fma2(ex2, x0, agg[0]); agg[1] = fma2(ex2, x1, agg[1]);  \
    agg[2] = fma2(ex2, x2, agg[2]); agg[3] = fma2(ex2, x3, agg[3]);  \
  }

__global__ __launch_bounds__(256) void node_attn_kernel(
    const float4* __restrict__ edata, const int* __restrict__ eord,
    const unsigned short* __restrict__ xl, const unsigned short* __restrict__ xr,
    const float* __restrict__ We, const float* __restrict__ att,
    const float* __restrict__ cbias, const float* __restrict__ gamma,
    const float* __restrict__ beta,
    const int* __restrict__ rowptr,
    const float* __restrict__ identity,
    float* __restrict__ alpha_out, float* __restrict__ denom_buf,
    unsigned short* __restrict__ hbuf)
{
  int wid  = threadIdx.x >> 6;
  int lane = threadIdx.x & 63;
  int v = blockIdx.x*4 + wid;
  if (v >= NN) return;
  int li   = lane & 31;
  int half = lane >> 5;
  int c0   = li * 8;
  int head = li >> 3;

  // loop-invariant per-lane state: 8 channels of We rows, att, x_r
  f32x2 w0[4], w1[4], w2[4], at4[4], xr4[4];
  {
    float4 a = ld4(We + c0),        b = ld4(We + c0 + 4);
    w0[0].x=a.x; w0[0].y=a.y; w0[1].x=a.z; w0[1].y=a.w;
    w0[2].x=b.x; w0[2].y=b.y; w0[3].x=b.z; w0[3].y=b.w;
    a = ld4(We + 256 + c0); b = ld4(We + 256 + c0 + 4);
    w1[0].x=a.x; w1[0].y=a.y; w1[1].x=a.z; w1[1].y=a.w;
    w1[2].x=b.x; w1[2].y=b.y; w1[3].x=b.z; w1[3].y=b.w;
    a = ld4(We + 512 + c0); b = ld4(We + 512 + c0 + 4);
    w2[0].x=a.x; w2[0].y=a.y; w2[1].x=a.z; w2[1].y=a.w;
    w2[2].x=b.x; w2[2].y=b.y; w2[3].x=b.z; w2[3].y=b.w;
    a = ld4(att + c0);      b = ld4(att + c0 + 4);
    at4[0].x=a.x; at4[0].y=a.y; at4[1].x=a.z; at4[1].y=a.w;
    at4[2].x=b.x; at4[2].y=b.y; at4[3].x=b.z; at4[3].y=b.w;
  }
  {
    uint4 xrq = *(const uint4*)(xr + (size_t)v*256 + c0);
    xr4[0] = unpk(xrq.x); xr4[1] = unpk(xrq.y);
    xr4[2] = unpk(xrq.z); xr4[3] = unpk(xrq.w);
  }
  const unsigned short* xlp = xl + c0;

  int rs = rowptr[v], re = rowptr[v+1];
  int deg = re - rs;
  int npairs = (deg + 1) >> 1;
  const int* eop = eord + rs;

  float denom = 0.f;
  f32x2 agg[4];
  agg[0]=set2(0.f); agg[1]=set2(0.f); agg[2]=set2(0.f); agg[3]=set2(0.f);

  if (npairs > 0) {
    float4 edA0, edA1, edA2, edA3;
    float4 edB0, edB1, edB2, edB3;
    uint4 qA0, qA1, qA2, qA3;
    uint4 qB0, qB1, qB2, qB3;

    LOAD_ED(0, edA0); LOAD_ED(1, edA1); LOAD_ED(2, edA2); LOAD_ED(3, edA3);
    LOAD_Q(edA0, qA0); LOAD_Q(edA1, qA1); LOAD_Q(edA2, qA2); LOAD_Q(edA3, qA3);

    int p = 0;
    while (true) {
      // group A live: pairs p..p+3 ; prefetch group B = pairs p+4..p+7
      if (p + 4 < npairs) {
        LOAD_ED(p+4, edB0); LOAD_ED(p+5, edB1);
        LOAD_ED(p+6, edB2); LOAD_ED(p+7, edB3);
        LOAD_Q(edB0, qB0); LOAD_Q(edB1, qB1);
        LOAD_Q(edB2, qB2); LOAD_Q(edB3, qB3);
      }
      PROC_E(p+0, edA0, qA0); PROC_E(p+1, edA1, qA1);
      PROC_E(p+2, edA2, qA2); PROC_E(p+3, edA3, qA3);
      p += 4;
      if (p >= npairs) break;

      // group B live: pairs p..p+3 ; prefetch group A = pairs p+4..p+7
      if (p + 4 < npairs) {
        LOAD_ED(p+4, edA0); LOAD_ED(p+5, edA1);
        LOAD_ED(p+6, edA2); LOAD_ED(p+7, edA3);
        LOAD_Q(edA0, qA0); LOAD_Q(edA1, qA1);
        LOAD_Q(edA2, qA2); LOAD_Q(edA3, qA3);
      }
      PROC_E(p+0, edB0, qB0); PROC_E(p+1, edB1, qB1);
      PROC_E(p+2, edB2, qB2); PROC_E(p+3, edB3, qB3);
      p += 4;
      if (p >= npairs) break;
    }
  }

  // combine the two halves (channels are duplicated across halves)
#pragma unroll
  for (int k = 0; k < 4; ++k) {
    agg[k].x += __shfl_xor(agg[k].x, 32, 64);
    agg[k].y += __shfl_xor(agg[k].y, 32, 64);
  }
  denom += __shfl_xor(denom, 32, 64);
  if (half == 0 && (li & 7) == 0) denom_buf[(size_t)v*4 + head] = denom;
  float rdenom = 1.0f / (denom + 1e-16f);

  float4 cb0 = ld4(cbias + c0), cb1 = ld4(cbias + c0 + 4);
  float a0 = agg[0].x*rdenom + cb0.x;
  float a1 = agg[0].y*rdenom + cb0.y;
  float a2 = agg[1].x*rdenom + cb0.z;
  float a3 = agg[1].y*rdenom + cb0.w;
  float a4 = agg[2].x*rdenom + cb1.x;
  float a5 = agg[2].y*rdenom + cb1.y;
  float a6 = agg[3].x*rdenom + cb1.z;
  float a7 = agg[3].y*rdenom + cb1.w;

  float ps  = ((a0+a1)+(a2+a3)) + ((a4+a5)+(a6+a7));
  float ps2 = ((a0*a0+a1*a1)+(a2*a2+a3*a3)) + ((a4*a4+a5*a5)+(a6*a6+a7*a7));
#pragma unroll
  for (int off = 1; off < 32; off <<= 1) {
    ps  += __shfl_xor(ps,  off, 64);
    ps2 += __shfl_xor(ps2, off, 64);
  }
  float mu  = ps  * (1.0f/256.0f);
  float var = ps2 * (1.0f/256.0f) - mu*mu;
  float rstd = rsqrtf(var + 1e-5f);
  float4 g0  = ld4(gamma + c0), g1 = ld4(gamma + c0 + 4);
  float4 bb0 = ld4(beta  + c0), bb1 = ld4(beta  + c0 + 4);
  float4 id0 = ld4(identity + (size_t)v*256 + c0);
  float4 id1 = ld4(identity + (size_t)v*256 + c0 + 4);

  float y0 = (a0 - mu)*rstd*g0.x + bb0.x;
  float y1 = (a1 - mu)*rstd*g0.y + bb0.y;
  float y2 = (a2 - mu)*rstd*g0.z + bb0.z;
  float y3 = (a3 - mu)*rstd*g0.w + bb0.w;
  float y4 = (a4 - mu)*rstd*g1.x + bb1.x;
  float y5 = (a5 - mu)*rstd*g1.y + bb1.y;
  float y6 = (a6 - mu)*rstd*g1.z + bb1.z;
  float y7 = (a7 - mu)*rstd*g1.w + bb1.w;
  y0 = y0 / (1.0f + __expf(-y0)) + id0.x;
  y1 = y1 / (1.0f + __expf(-y1)) + id0.y;
  y2 = y2 / (1.0f + __expf(-y2)) + id0.z;
  y3 = y3 / (1.0f + __expf(-y3)) + id0.w;
  y4 = y4 / (1.0f + __expf(-y4)) + id1.x;
  y5 = y5 / (1.0f + __expf(-y5)) + id1.y;
  y6 = y6 / (1.0f + __expf(-y6)) + id1.z;
  y7 = y7 / (1.0f + __expf(-y7)) + id1.w;

  if (half == 0) {
    uint4 hq;
    hq.x = (unsigned)f2b(y0) | ((unsigned)f2b(y1) << 16);
    hq.y = (unsigned)f2b(y2) | ((unsigned)f2b(y3) << 16);
    hq.z = (unsigned)f2b(y4) | ((unsigned)f2b(y5) << 16);
    hq.w = (unsigned)f2b(y6) | ((unsigned)f2b(y7) << 16);
    *(uint4*)(hbuf + (size_t)v*256 + c0) = hq;
  }
}

// ---------------- finalize alpha: alpha[e,h] = ex[e,h] / (denom[dst,h]+1e-16) ----------------
__global__ void alpha_fin_kernel(const int* __restrict__ ei, const float* __restrict__ denom_buf,
                                 float* __restrict__ alpha)
{
  int e = blockIdx.x*blockDim.x + threadIdx.x;
  if (e >= EE) return;
  int d = ei[EE + e];
  float4 dn = ld4(denom_buf + (size_t)d*4);
  float4 a = ld4(alpha + (size_t)e*4);
  a.x /= (dn.x + 1e-16f);
  a.y /= (dn.y + 1e-16f);
  a.z /= (dn.z + 1e-16f);
  a.w /= (dn.w + 1e-16f);
  *(float4*)(alpha + (size_t)e*4) = a;
}

extern "C" void kernel_launch(void* const* d_in, const int* in_sizes, int n_in,
                              void* d_out, int out_size, void* d_ws, size_t ws_size,
                              hipStream_t stream)
{
  const float* x      = (const float*)d_in[0];
  const float* kpts   = (const float*)d_in[1];
  const float* pts3d  = (const float*)d_in[2];
  const int*   ei     = (const int*)d_in[3];
  const float* W1     = (const float*)d_in[4];
  const float* b1     = (const float*)d_in[5];
  const float* W2     = (const float*)d_in[6];
  const float* b2     = (const float*)d_in[7];
  const float* Wres   = (const float*)d_in[8];
  const float* bres   = (const float*)d_in[9];
  const float* Wl     = (const float*)d_in[10];
  const float* bl     = (const float*)d_in[11];
  const float* Wr     = (const float*)d_in[12];
  const float* br     = (const float*)d_in[13];
  const float* We     = (const float*)d_in[14];
  const float* att    = (const float*)d_in[15];
  const float* cbias  = (const float*)d_in[16];
  const float* gamma  = (const float*)d_in[17];
  const float* beta   = (const float*)d_in[18];
  const float* Wp     = (const float*)d_in[19];
  const float* bp     = (const float*)d_in[20];

  float* out       = (float*)d_out;
  float* alpha_out = out + (size_t)NN*HIDC;

  // workspace layout (units: float elements) — ~153 MB
  float* wsf = (float*)d_ws;
  float*          identity = wsf;                               // 12,800,000 f
  unsigned short* xl       = (unsigned short*)(wsf + 12800000); // 12,812,288 us
  unsigned short* xr       = (unsigned short*)(wsf + 19206144);
  unsigned short* nodex    = (unsigned short*)(wsf + 25612288); // 16,015,360 us
  unsigned short* hbuf     = (unsigned short*)(wsf + 25612288); // alias nodex (dead after gemm3)
  unsigned short* wt       = (unsigned short*)(wsf + 33619968); // 311,296 us
  float*          biascat  = wsf + 33775616;                    // 768 f
  float*          denomb   = wsf + 33776384;                    // 200,000 f
  float4*         edata    = (float4*)(wsf + 33976384);         // 800,000 float4
  int*            eord     = (int*)(wsf + 37176384);            // 800,000 i
  int*            incl     = (int*)(wsf + 37176384);            // alias eord (dead before scatter)
  int*            deg      = (int*)(wsf + 37976384);            // 50,000 i
  int*            rowptr   = (int*)(wsf + 38026384);            // 50,001 i
  int*            cursor   = (int*)(wsf + 38076385);            // 50,000 i
  int*            bsum     = (int*)(wsf + 38126385);            // 64 i

  unsigned short* wtcat = wt;            // 768 x 320 (Wres_T | Wl_T | Wr_T)
  unsigned short* wtp   = wt + 245760;   // 256 x 256

  cvt_x_kernel<<<12500, 256, 0, stream>>>(x, nodex);
  node_mlp_kernel<<<(NN+255)/256, 256, 0, stream>>>(kpts, pts3d, W1, b1, W2, b2, nodex);
  cvt_w_kernel<<<1219, 256, 0, stream>>>(Wres, Wl, Wr, Wp, bres, bl, br, wt, biascat);

  // fused triple GEMM: [identity | x_l | x_r] = nodex @ [Wres|Wl|Wr] + [bres|bl|br]
  dim3 g3(NPAD/128, 6);
  mfma_gemm_kernel<<<g3, 256, 0, stream>>>(nodex, wtcat, biascat, identity, xl, xr, NN, INCH);

  hipMemsetAsync(deg, 0, NN*sizeof(int), stream);
  hist_kernel<<<(EE+255)/256, 256, 0, stream>>>(ei, deg);
  int nblk = (NN + 1023) / 1024;   // 49
  scan1_kernel<<<nblk, 1024, 0, stream>>>(deg, incl, bsum);
  scan2_kernel<<<1, 64, 0, stream>>>(bsum, nblk);
  scan3_kernel<<<nblk, 1024, 0, stream>>>(incl, deg, bsum, rowptr, cursor, nblk);
  scatter_kernel<<<(EE+255)/256, 256, 0, stream>>>(ei, kpts, cursor, edata, eord);

  node_attn_kernel<<<(NN+3)/4, 256, 0, stream>>>(edata, eord, xl, xr, We, att,
                                                 cbias, gamma, beta,
                                                 rowptr, identity,
                                                 alpha_out, denomb, hbuf);
  alpha_fin_kernel<<<(EE+255)/256, 256, 0, stream>>>(ei, denomb, alpha_out);

  dim3 g1(NPAD/128, 2);
  mfma_gemm_kernel<<<g1, 256, 0, stream>>>(hbuf, wtp, bp, out, nullptr, nullptr, NN, HIDC);
}

// Round 3
// 547.091 us; speedup vs baseline: 1.1788x; 1.1788x over previous
//
#include <hip/hip_runtime.h>
#include <math.h>

#define NN 50000
#define NPAD 50048
#define EE 800000
#define HIDC 256
#define INCH 320

typedef __attribute__((ext_vector_type(8))) short bf16x8;
typedef __attribute__((ext_vector_type(4))) float f32x4;
typedef __attribute__((ext_vector_type(2))) float f32x2;

static __device__ __forceinline__ float4 ld4(const float* p){ return *(const float4*)p; }

static __device__ __forceinline__ unsigned short f2b(float f){
  union { float f; unsigned u; } v; v.f = f;
  unsigned r = v.u + 0x7fffu + ((v.u >> 16) & 1u);
  return (unsigned short)(r >> 16);
}
static __device__ __forceinline__ float b2f(unsigned short u){
  union { unsigned u; float f; } v; v.u = ((unsigned)u) << 16; return v.f;
}
static __device__ __forceinline__ float rlane_f(float v, int l){
  return __uint_as_float(__builtin_amdgcn_readlane(__float_as_uint(v), l));
}
static __device__ __forceinline__ int rlane_i(int v, int l){
  return __builtin_amdgcn_readlane(v, l);
}
// unpack two bf16 packed in a u32 -> 2 floats (lo = .x, hi = .y)
static __device__ __forceinline__ f32x2 unpk(unsigned u){
  f32x2 r;
  r.x = __uint_as_float(u << 16);
  r.y = __uint_as_float(u & 0xffff0000u);
  return r;
}
static __device__ __forceinline__ f32x2 fma2(f32x2 a, f32x2 b, f32x2 c){
  return __builtin_elementwise_fma(a, b, c);
}
static __device__ __forceinline__ f32x2 max2(f32x2 a, f32x2 b){
  return __builtin_elementwise_max(a, b);
}
static __device__ __forceinline__ f32x2 set2(float v){ f32x2 r; r.x = v; r.y = v; return r; }

typedef const __attribute__((address_space(1))) unsigned int* gas_u32;
typedef __attribute__((address_space(3))) unsigned int* las_u32;
static __device__ __forceinline__ void gload_lds16(const void* g, void* l){
  __builtin_amdgcn_global_load_lds((gas_u32)g, (las_u32)l, 16, 0, 0);
}

// ---------------- convert x (fp32 50000x256) into node_x bf16 (NPAD x 320, cols 0..255) ----------------
__global__ void cvt_x_kernel(const float* __restrict__ x, unsigned short* __restrict__ nodex)
{
  int t = blockIdx.x*blockDim.x + threadIdx.x;
  int row = t >> 6;
  if (row >= NN) return;
  int c4 = (t & 63) * 4;
  float4 v = ld4(x + (size_t)row*256 + c4);
  ushort4 o;
  o.x = f2b(v.x); o.y = f2b(v.y); o.z = f2b(v.z); o.w = f2b(v.w);
  *(ushort4*)(nodex + (size_t)row*320 + c4) = o;
}

// ---------------- node positional MLP: writes bf16 into node_x cols 256..319 ----------------
__global__ void node_mlp_kernel(const float* __restrict__ kpts,
                                const float* __restrict__ pts3d,
                                const float* __restrict__ W1, const float* __restrict__ b1,
                                const float* __restrict__ W2, const float* __restrict__ b2,
                                unsigned short* __restrict__ nodex)
{
  int i = blockIdx.x*blockDim.x + threadIdx.x;
  if (i >= NN) return;
  float u = kpts[2*i]   * (1.0f/1216.0f);
  float v = kpts[2*i+1] * (1.0f/352.0f);
  float d = pts3d[3*i+2];
  float h[32];
#pragma unroll
  for (int j=0;j<32;++j){
    float t = u*W1[j] + v*W1[32+j] + d*W1[64+j] + b1[j];
    h[j] = t / (1.0f + __expf(-t));   // silu
  }
  for (int o=0;o<64;o+=4){
    float s0=b2[o], s1=b2[o+1], s2=b2[o+2], s3=b2[o+3];
#pragma unroll
    for (int j=0;j<32;++j){
      float hj = h[j];
      const float* w = W2 + j*64 + o;
      s0 += hj*w[0]; s1 += hj*w[1]; s2 += hj*w[2]; s3 += hj*w[3];
    }
    ushort4 r; r.x=f2b(s0); r.y=f2b(s1); r.z=f2b(s2); r.w=f2b(s3);
    *(ushort4*)(nodex + (size_t)i*320 + 256 + o) = r;
  }
}

// ---------------- convert + transpose weights to bf16 N-major (K contiguous) + bias concat ----------------
__global__ void cvt_w_kernel(const float* __restrict__ Wres, const float* __restrict__ Wl,
                             const float* __restrict__ Wr,   const float* __restrict__ Wp,
                             const float* __restrict__ bres, const float* __restrict__ bl,
                             const float* __restrict__ br,
                             unsigned short* __restrict__ wt, float* __restrict__ biascat)
{
  int t = blockIdx.x*blockDim.x + threadIdx.x;   // 312064 threads
  if (t < 245760) {
    int which = t / 81920;
    int rem = t % 81920;
    int n = rem / 320, k = rem % 320;
    const float* W = (which == 0) ? Wres : (which == 1) ? Wl : Wr;
    wt[(size_t)which*81920 + rem] = f2b(W[(size_t)k*256 + n]);
  } else if (t < 311296) {
    int r = t - 245760;
    int n = r / 256, k = r % 256;
    wt[245760 + r] = f2b(Wp[(size_t)k*256 + n]);
  } else {
    int r = t - 311296;   // 0..767
    const float* src = (r < 256) ? bres : (r < 512) ? bl : br;
    biascat[r] = src[r & 255];
  }
}

// ---------------- bf16 MFMA GEMM: C(M,Nt) = A(M,K) @ BT(Nt,K)^T + bias ----------------
#define GK 32
__global__ __launch_bounds__(256) void mfma_gemm_kernel(
    const unsigned short* __restrict__ A,
    const unsigned short* __restrict__ BT,
    const float* __restrict__ bias,
    float* __restrict__ Cf,
    unsigned short* __restrict__ Cx1,
    unsigned short* __restrict__ Cx2,
    int M, int K)
{
  __shared__ unsigned short Als[128*GK];
  __shared__ unsigned short Bls[128*GK];
  int tid = threadIdx.x;
  int lane = tid & 63, wave = tid >> 6;
  int wm = (wave >> 1) * 64, wn = (wave & 1) * 64;
  int row0 = blockIdx.x * 128, col0 = blockIdx.y * 128;

  f32x4 acc[4][4];
#pragma unroll
  for (int i=0;i<4;++i)
#pragma unroll
    for (int j=0;j<4;++j){ acc[i][j].x=0.f; acc[i][j].y=0.f; acc[i][j].z=0.f; acc[i][j].w=0.f; }

  int fm = lane & 15;
  int fk = (lane >> 4) * 8;

  for (int k0 = 0; k0 < K; k0 += GK) {
#pragma unroll
    for (int it = 0; it < 2; ++it) {
      int seg = it*256 + tid;
      int r = seg >> 2, kb = (seg & 3) * 8;
      gload_lds16(A  + (size_t)(row0 + r)*K + k0 + kb, Als + (it*256 + wave*64)*8);
      gload_lds16(BT + (size_t)(col0 + r)*K + k0 + kb, Bls + (it*256 + wave*64)*8);
    }
    __syncthreads();

    bf16x8 af[4], bfr[4];
#pragma unroll
    for (int mi=0; mi<4; ++mi)
      af[mi] = *(const bf16x8*)&Als[(wm + mi*16 + fm)*GK + fk];
#pragma unroll
    for (int ni=0; ni<4; ++ni)
      bfr[ni] = *(const bf16x8*)&Bls[(wn + ni*16 + fm)*GK + fk];
#pragma unroll
    for (int mi=0; mi<4; ++mi)
#pragma unroll
      for (int ni=0; ni<4; ++ni)
        acc[mi][ni] = __builtin_amdgcn_mfma_f32_16x16x32_bf16(af[mi], bfr[ni], acc[mi][ni], 0, 0, 0);
    __syncthreads();
  }

  int seg = col0 >> 8;
  int colbase = col0 - seg*256;
  int cn = lane & 15, cr = (lane >> 4) * 4;
#pragma unroll
  for (int ni=0; ni<4; ++ni){
    int gcol = col0 + wn + ni*16 + cn;
    int col  = colbase + wn + ni*16 + cn;
    float bb = bias[gcol];
#pragma unroll
    for (int mi=0; mi<4; ++mi){
#pragma unroll
      for (int r=0; r<4; ++r){
        int row = row0 + wm + mi*16 + cr + r;
        if (row < M){
          float v = acc[mi][ni][r] + bb;
          if (seg == 0)      Cf [(size_t)row*256 + col] = v;
          else if (seg == 1) Cx1[(size_t)row*256 + col] = f2b(v);
          else               Cx2[(size_t)row*256 + col] = f2b(v);
        }
      }
    }
  }
}

// ---------------- CSR build by dst ----------------
__global__ void hist_kernel(const int* __restrict__ ei, int* __restrict__ deg){
  int e = blockIdx.x*blockDim.x + threadIdx.x;
  if (e < EE) atomicAdd(&deg[ei[EE + e]], 1);
}

// parallel 3-phase scan
__global__ __launch_bounds__(1024) void scan1_kernel(const int* __restrict__ deg,
                                                     int* __restrict__ incl, int* __restrict__ bsum){
  __shared__ int wsums[16];
  int t = threadIdx.x, lane = t & 63, w = t >> 6;
  int i = blockIdx.x*1024 + t;
  int v = (i < NN) ? deg[i] : 0;
  int sc = v;
#pragma unroll
  for (int off = 1; off < 64; off <<= 1) {
    int o = __shfl_up(sc, off, 64);
    if (lane >= off) sc += o;
  }
  if (lane == 63) wsums[w] = sc;
  __syncthreads();
  if (w == 0) {
    int ws = (lane < 16) ? wsums[lane] : 0;
#pragma unroll
    for (int off = 1; off < 16; off <<= 1) {
      int o = __shfl_up(ws, off, 64);
      if (lane >= off) ws += o;
    }
    if (lane < 16) wsums[lane] = ws;
  }
  __syncthreads();
  int woff = (w > 0) ? wsums[w-1] : 0;
  if (i < NN) incl[i] = sc + woff;
  if (t == 1023) bsum[blockIdx.x] = woff + sc;
}

__global__ void scan2_kernel(int* __restrict__ bsum, int nblk){
  int lane = threadIdx.x;
  int v = (lane < nblk) ? bsum[lane] : 0;
#pragma unroll
  for (int off = 1; off < 64; off <<= 1) {
    int o = __shfl_up(v, off, 64);
    if (lane >= off) v += o;
  }
  if (lane < nblk) bsum[lane] = v;
}

__global__ __launch_bounds__(1024) void scan3_kernel(const int* __restrict__ incl,
                                                     const int* __restrict__ deg,
                                                     const int* __restrict__ bsum,
                                                     int* __restrict__ rowptr, int* __restrict__ cursor,
                                                     int nblk){
  int i = blockIdx.x*1024 + threadIdx.x;
  if (i < NN) {
    int b = blockIdx.x;
    int prev = (b > 0) ? bsum[b-1] : 0;
    int ex = prev + incl[i] - deg[i];
    rowptr[i] = ex;
    cursor[i] = ex;
  }
  if (i == 0) rowptr[NN] = bsum[nblk-1];
}

// scatter: place edge into its dst bin AND precompute edge geometry
__global__ void scatter_kernel(const int* __restrict__ ei, const float* __restrict__ kpts,
                               int* __restrict__ cursor,
                               float4* __restrict__ edata, int* __restrict__ eord){
  int e = blockIdx.x*blockDim.x + threadIdx.x;
  if (e >= EE) return;
  int s = ei[e];
  int d = ei[EE + e];
  int pos = atomicAdd(&cursor[d], 1);
  float su = kpts[2*s]   * (1.0f/1216.0f);
  float sv = kpts[2*s+1] * (1.0f/352.0f);
  float du = kpts[2*d]   * (1.0f/1216.0f);
  float dv = kpts[2*d+1] * (1.0f/352.0f);
  float ru = du - su, rv = dv - sv;
  float dist = sqrtf(ru*ru + rv*rv);
  float4 ed; ed.x = ru; ed.y = rv; ed.z = dist; ed.w = __int_as_float(s);
  edata[pos] = ed;
  eord[pos] = e;
}

// ---------------- per-node attention: batched 8-deep gather pipeline + packed fp32 ----------------
// (round-0 structure: 1 wave per node, 64 lanes x 4 channels, readlane-broadcast
//  edge scalars, 8-deep flat gather pipeline. 48 VGPR -> 8 waves/SIMD.)
#define LOAD8(Q, B0)                                               \
  if ((B0) < cnt) {                                                \
    _Pragma("unroll")                                              \
    for (int t = 0; t < 8; ++t) {                                  \
      int sj = rlane_i(s, ((B0) + t) & 63);                        \
      Q[t] = *(const uint2*)(xlp + ((size_t)sj << 8));             \
    }                                                              \
  }

#define PROC8(Q, B0)                                               \
  _Pragma("unroll")                                                \
  for (int t = 0; t < 8; ++t) {                                    \
    int j = (B0) + t;                                              \
    if (j < cnt) {                                                 \
      float ruj = rlane_f(ed.x, j);                                \
      float rvj = rlane_f(ed.y, j);                                \
      float dj  = rlane_f(ed.z, j);                                \
      f32x2 x01 = unpk(Q[t].x), x23 = unpk(Q[t].y);                \
      f32x2 t01 = fma2(set2(ruj), we0a, xr01);                     \
      t01 = fma2(set2(rvj), we1a, t01);                            \
      t01 = fma2(set2(dj),  we2a, t01);                            \
      t01 = t01 + x01;                                             \
      f32x2 t23 = fma2(set2(ruj), we0b, xr23);                     \
      t23 = fma2(set2(rvj), we1b, t23);                            \
      t23 = fma2(set2(dj),  we2b, t23);                            \
      t23 = t23 + x23;                                             \
      t01 = max2(t01, t01*0.2f);                                   \
      t23 = max2(t23, t23*0.2f);                                   \
      f32x2 pd = t01*atta;                                         \
      pd = fma2(t23, attb, pd);                                    \
      float p = pd.x + pd.y;                                       \
      p += __shfl_xor(p, 1, 64);                                   \
      p += __shfl_xor(p, 2, 64);                                   \
      p += __shfl_xor(p, 4, 64);                                   \
      p += __shfl_xor(p, 8, 64);                                   \
      float exv = __expf(p);                                       \
      denom += exv;                                                \
      int ej = rlane_i(e, j);                                      \
      if ((lane & 15) == 0) alpha_out[(size_t)ej*4 + head] = exv;  \
      f32x2 ex2 = set2(exv);                                       \
      agg01 = fma2(ex2, x01, agg01);                               \
      agg23 = fma2(ex2, x23, agg23);                               \
    }                                                              \
  }

__global__ __launch_bounds__(128) void node_attn_kernel(
    const float4* __restrict__ edata, const int* __restrict__ eord,
    const unsigned short* __restrict__ xl, const unsigned short* __restrict__ xr,
    const float* __restrict__ We, const float* __restrict__ att,
    const float* __restrict__ cbias, const float* __restrict__ gamma,
    const float* __restrict__ beta,
    const int* __restrict__ rowptr,
    const float* __restrict__ identity,
    float* __restrict__ alpha_out, float* __restrict__ denom_buf,
    unsigned short* __restrict__ hbuf)
{
  int wid  = threadIdx.x >> 6;
  int lane = threadIdx.x & 63;
  int v = blockIdx.x*2 + wid;
  if (v >= NN) return;
  int c0 = lane*4;
  int head = lane >> 4;

  f32x2 we0a, we0b, we1a, we1b, we2a, we2b, atta, attb;
  we0a.x = We[c0];       we0a.y = We[c0+1];       we0b.x = We[c0+2];       we0b.y = We[c0+3];
  we1a.x = We[256+c0];   we1a.y = We[256+c0+1];   we1b.x = We[256+c0+2];   we1b.y = We[256+c0+3];
  we2a.x = We[512+c0];   we2a.y = We[512+c0+1];   we2b.x = We[512+c0+2];   we2b.y = We[512+c0+3];
  atta.x = att[c0];      atta.y = att[c0+1];      attb.x = att[c0+2];      attb.y = att[c0+3];
  uint2 xrq = *(const uint2*)(xr + (size_t)v*256 + c0);
  f32x2 xr01 = unpk(xrq.x), xr23 = unpk(xrq.y);
  const unsigned short* xlp = xl + c0;

  int rs = rowptr[v], re = rowptr[v+1];
  int deg = re - rs;

  float denom = 0.f;
  f32x2 agg01 = set2(0.f), agg23 = set2(0.f);

  for (int base = 0; base < deg; base += 64) {
    int cnt = min(64, deg - base);
    float4 ed; ed.x = 0.f; ed.y = 0.f; ed.z = 0.f; ed.w = __int_as_float(0);
    int e = 0;
    if (lane < cnt) {
      ed = edata[rs + base + lane];
      e  = eord [rs + base + lane];
    }
    int s = __float_as_int(ed.w);

    uint2 qa[8], qb[8];
    LOAD8(qa, 0);
    for (int b0 = 0; b0 < cnt; b0 += 16) {
      LOAD8(qb, b0 + 8);
      PROC8(qa, b0);
      LOAD8(qa, b0 + 16);
      PROC8(qb, b0 + 8);
    }
  }

  float rdenom = 1.0f / (denom + 1e-16f);
  if ((lane & 15) == 0) denom_buf[(size_t)v*4 + head] = denom;

  float a0 = agg01.x*rdenom + cbias[c0];
  float a1 = agg01.y*rdenom + cbias[c0+1];
  float a2 = agg23.x*rdenom + cbias[c0+2];
  float a3 = agg23.y*rdenom + cbias[c0+3];

  float ps  = a0 + a1 + a2 + a3;
  float ps2 = a0*a0 + a1*a1 + a2*a2 + a3*a3;
#pragma unroll
  for (int off = 1; off < 64; off <<= 1) {
    ps  += __shfl_xor(ps,  off, 64);
    ps2 += __shfl_xor(ps2, off, 64);
  }
  float mu  = ps  * (1.0f/256.0f);
  float var = ps2 * (1.0f/256.0f) - mu*mu;
  float rstd = rsqrtf(var + 1e-5f);
  float4 g  = ld4(gamma + c0);
  float4 b  = ld4(beta  + c0);
  float4 idv = ld4(identity + (size_t)v*256 + c0);
  float y0 = (a0 - mu)*rstd*g.x + b.x;
  float y1 = (a1 - mu)*rstd*g.y + b.y;
  float y2 = (a2 - mu)*rstd*g.z + b.z;
  float y3 = (a3 - mu)*rstd*g.w + b.w;
  y0 = y0 / (1.0f + __expf(-y0)) + idv.x;
  y1 = y1 / (1.0f + __expf(-y1)) + idv.y;
  y2 = y2 / (1.0f + __expf(-y2)) + idv.z;
  y3 = y3 / (1.0f + __expf(-y3)) + idv.w;
  ushort4 hq; hq.x=f2b(y0); hq.y=f2b(y1); hq.z=f2b(y2); hq.w=f2b(y3);
  *(ushort4*)(hbuf + (size_t)v*256 + c0) = hq;
}

// ---------------- finalize alpha: alpha[e,h] = ex[e,h] / (denom[dst,h]+1e-16) ----------------
__global__ void alpha_fin_kernel(const int* __restrict__ ei, const float* __restrict__ denom_buf,
                                 float* __restrict__ alpha)
{
  int e = blockIdx.x*blockDim.x + threadIdx.x;
  if (e >= EE) return;
  int d = ei[EE + e];
  float4 dn = ld4(denom_buf + (size_t)d*4);
  float4 a = ld4(alpha + (size_t)e*4);
  a.x /= (dn.x + 1e-16f);
  a.y /= (dn.y + 1e-16f);
  a.z /= (dn.z + 1e-16f);
  a.w /= (dn.w + 1e-16f);
  *(float4*)(alpha + (size_t)e*4) = a;
}

extern "C" void kernel_launch(void* const* d_in, const int* in_sizes, int n_in,
                              void* d_out, int out_size, void* d_ws, size_t ws_size,
                              hipStream_t stream)
{
  const float* x      = (const float*)d_in[0];
  const float* kpts   = (const float*)d_in[1];
  const float* pts3d  = (const float*)d_in[2];
  const int*   ei     = (const int*)d_in[3];
  const float* W1     = (const float*)d_in[4];
  const float* b1     = (const float*)d_in[5];
  const float* W2     = (const float*)d_in[6];
  const float* b2     = (const float*)d_in[7];
  const float* Wres   = (const float*)d_in[8];
  const float* bres   = (const float*)d_in[9];
  const float* Wl     = (const float*)d_in[10];
  const float* bl     = (const float*)d_in[11];
  const float* Wr     = (const float*)d_in[12];
  const float* br     = (const float*)d_in[13];
  const float* We     = (const float*)d_in[14];
  const float* att    = (const float*)d_in[15];
  const float* cbias  = (const float*)d_in[16];
  const float* gamma  = (const float*)d_in[17];
  const float* beta   = (const float*)d_in[18];
  const float* Wp     = (const float*)d_in[19];
  const float* bp     = (const float*)d_in[20];

  float* out       = (float*)d_out;
  float* alpha_out = out + (size_t)NN*HIDC;

  // workspace layout (units: float elements) — ~153 MB
  float* wsf = (float*)d_ws;
  float*          identity = wsf;                               // 12,800,000 f
  unsigned short* xl       = (unsigned short*)(wsf + 12800000); // 12,812,288 us
  unsigned short* xr       = (unsigned short*)(wsf + 19206144);
  unsigned short* nodex    = (unsigned short*)(wsf + 25612288); // 16,015,360 us
  unsigned short* hbuf     = (unsigned short*)(wsf + 25612288); // alias nodex (dead after gemm3)
  unsigned short* wt       = (unsigned short*)(wsf + 33619968); // 311,296 us
  float*          biascat  = wsf + 33775616;                    // 768 f
  float*          denomb   = wsf + 33776384;                    // 200,000 f
  float4*         edata    = (float4*)(wsf + 33976384);         // 800,000 float4
  int*            eord     = (int*)(wsf + 37176384);            // 800,000 i
  int*            incl     = (int*)(wsf + 37176384);            // alias eord (dead before scatter)
  int*            deg      = (int*)(wsf + 37976384);            // 50,000 i
  int*            rowptr   = (int*)(wsf + 38026384);            // 50,001 i
  int*            cursor   = (int*)(wsf + 38076385);            // 50,000 i
  int*            bsum     = (int*)(wsf + 38126385);            // 64 i

  unsigned short* wtcat = wt;            // 768 x 320 (Wres_T | Wl_T | Wr_T)
  unsigned short* wtp   = wt + 245760;   // 256 x 256

  cvt_x_kernel<<<12500, 256, 0, stream>>>(x, nodex);
  node_mlp_kernel<<<(NN+255)/256, 256, 0, stream>>>(kpts, pts3d, W1, b1, W2, b2, nodex);
  cvt_w_kernel<<<1219, 256, 0, stream>>>(Wres, Wl, Wr, Wp, bres, bl, br, wt, biascat);

  // fused triple GEMM: [identity | x_l | x_r] = nodex @ [Wres|Wl|Wr] + [bres|bl|br]
  dim3 g3(NPAD/128, 6);
  mfma_gemm_kernel<<<g3, 256, 0, stream>>>(nodex, wtcat, biascat, identity, xl, xr, NN, INCH);

  hipMemsetAsync(deg, 0, NN*sizeof(int), stream);
  hist_kernel<<<(EE+255)/256, 256, 0, stream>>>(ei, deg);
  int nblk = (NN + 1023) / 1024;   // 49
  scan1_kernel<<<nblk, 1024, 0, stream>>>(deg, incl, bsum);
  scan2_kernel<<<1, 64, 0, stream>>>(bsum, nblk);
  scan3_kernel<<<nblk, 1024, 0, stream>>>(incl, deg, bsum, rowptr, cursor, nblk);
  scatter_kernel<<<(EE+255)/256, 256, 0, stream>>>(ei, kpts, cursor, edata, eord);

  node_attn_kernel<<<(NN+1)/2, 128, 0, stream>>>(edata, eord, xl, xr, We, att,
                                                 cbias, gamma, beta,
                                                 rowptr, identity,
                                                 alpha_out, denomb, hbuf);
  alpha_fin_kernel<<<(EE+255)/256, 256, 0, stream>>>(ei, denomb, alpha_out);

  dim3 g1(NPAD/128, 2);
  mfma_gemm_kernel<<<g1, 256, 0, stream>>>(hbuf, wtp, bp, out, nullptr, nullptr, NN, HIDC);
}

// Round 4
// 540.091 us; speedup vs baseline: 1.1941x; 1.0130x over previous
//
#include <hip/hip_runtime.h>
#include <math.h>

#define NN 50000
#define NPAD 50048
#define EE 800000
#define HIDC 256
#define INCH 320

typedef __attribute__((ext_vector_type(8))) short bf16x8;
typedef __attribute__((ext_vector_type(4))) float f32x4;
typedef __attribute__((ext_vector_type(2))) float f32x2;

static __device__ __forceinline__ float4 ld4(const float* p){ return *(const float4*)p; }

static __device__ __forceinline__ unsigned short f2b(float f){
  union { float f; unsigned u; } v; v.f = f;
  unsigned r = v.u + 0x7fffu + ((v.u >> 16) & 1u);
  return (unsigned short)(r >> 16);
}
static __device__ __forceinline__ float b2f(unsigned short u){
  union { unsigned u; float f; } v; v.u = ((unsigned)u) << 16; return v.f;
}
static __device__ __forceinline__ float rlane_f(float v, int l){
  return __uint_as_float(__builtin_amdgcn_readlane(__float_as_uint(v), l));
}
static __device__ __forceinline__ int rlane_i(int v, int l){
  return __builtin_amdgcn_readlane(v, l);
}
// unpack two bf16 packed in a u32 -> 2 floats (lo = .x, hi = .y)
static __device__ __forceinline__ f32x2 unpk(unsigned u){
  f32x2 r;
  r.x = __uint_as_float(u << 16);
  r.y = __uint_as_float(u & 0xffff0000u);
  return r;
}
static __device__ __forceinline__ f32x2 fma2(f32x2 a, f32x2 b, f32x2 c){
  return __builtin_elementwise_fma(a, b, c);
}
static __device__ __forceinline__ f32x2 max2(f32x2 a, f32x2 b){
  return __builtin_elementwise_max(a, b);
}
static __device__ __forceinline__ f32x2 set2(float v){ f32x2 r; r.x = v; r.y = v; return r; }

typedef const __attribute__((address_space(1))) unsigned int* gas_u32;
typedef __attribute__((address_space(3))) unsigned int* las_u32;
static __device__ __forceinline__ void gload_lds16(const void* g, void* l){
  __builtin_amdgcn_global_load_lds((gas_u32)g, (las_u32)l, 16, 0, 0);
}

// ---------------- convert x (fp32 50000x256) into node_x bf16 (NPAD x 320, cols 0..255) ----------------
__global__ void cvt_x_kernel(const float* __restrict__ x, unsigned short* __restrict__ nodex)
{
  int t = blockIdx.x*blockDim.x + threadIdx.x;
  int row = t >> 6;
  if (row >= NN) return;
  int c4 = (t & 63) * 4;
  float4 v = ld4(x + (size_t)row*256 + c4);
  ushort4 o;
  o.x = f2b(v.x); o.y = f2b(v.y); o.z = f2b(v.z); o.w = f2b(v.w);
  *(ushort4*)(nodex + (size_t)row*320 + c4) = o;
}

// ---------------- node positional MLP: writes bf16 into node_x cols 256..319 ----------------
__global__ void node_mlp_kernel(const float* __restrict__ kpts,
                                const float* __restrict__ pts3d,
                                const float* __restrict__ W1, const float* __restrict__ b1,
                                const float* __restrict__ W2, const float* __restrict__ b2,
                                unsigned short* __restrict__ nodex)
{
  int i = blockIdx.x*blockDim.x + threadIdx.x;
  if (i >= NN) return;
  float u = kpts[2*i]   * (1.0f/1216.0f);
  float v = kpts[2*i+1] * (1.0f/352.0f);
  float d = pts3d[3*i+2];
  float h[32];
#pragma unroll
  for (int j=0;j<32;++j){
    float t = u*W1[j] + v*W1[32+j] + d*W1[64+j] + b1[j];
    h[j] = t / (1.0f + __expf(-t));   // silu
  }
  for (int o=0;o<64;o+=4){
    float s0=b2[o], s1=b2[o+1], s2=b2[o+2], s3=b2[o+3];
#pragma unroll
    for (int j=0;j<32;++j){
      float hj = h[j];
      const float* w = W2 + j*64 + o;
      s0 += hj*w[0]; s1 += hj*w[1]; s2 += hj*w[2]; s3 += hj*w[3];
    }
    ushort4 r; r.x=f2b(s0); r.y=f2b(s1); r.z=f2b(s2); r.w=f2b(s3);
    *(ushort4*)(nodex + (size_t)i*320 + 256 + o) = r;
  }
}

// ---------------- convert + transpose weights to bf16 N-major (K contiguous) + bias concat ----------------
__global__ void cvt_w_kernel(const float* __restrict__ Wres, const float* __restrict__ Wl,
                             const float* __restrict__ Wr,   const float* __restrict__ Wp,
                             const float* __restrict__ bres, const float* __restrict__ bl,
                             const float* __restrict__ br,
                             unsigned short* __restrict__ wt, float* __restrict__ biascat)
{
  int t = blockIdx.x*blockDim.x + threadIdx.x;   // 312064 threads
  if (t < 245760) {
    int which = t / 81920;
    int rem = t % 81920;
    int n = rem / 320, k = rem % 320;
    const float* W = (which == 0) ? Wres : (which == 1) ? Wl : Wr;
    wt[(size_t)which*81920 + rem] = f2b(W[(size_t)k*256 + n]);
  } else if (t < 311296) {
    int r = t - 245760;
    int n = r / 256, k = r % 256;
    wt[245760 + r] = f2b(Wp[(size_t)k*256 + n]);
  } else {
    int r = t - 311296;   // 0..767
    const float* src = (r < 256) ? bres : (r < 512) ? bl : br;
    biascat[r] = src[r & 255];
  }
}

// ---------------- bf16 MFMA GEMM: C(M,Nt) = A(M,K) @ BT(Nt,K)^T + bias ----------------
// GK=64: half the barrier drains of GK=32 (K=320 -> 5 steps, K=256 -> 4).
// LDS rows are 128B -> ds_read_b128 would be a 16-way bank conflict unswizzled;
// XOR slot-swizzle (slot ^= row&7) applied on BOTH the pre-swizzled global
// source (LDS dest stays linear for global_load_lds) and the read side
// restores the 8-lane BW floor. FP accumulation order identical to GK=32
// (kk=0 then kk=1 == two consecutive old K-steps).
#define GK 64
__global__ __launch_bounds__(256) void mfma_gemm_kernel(
    const unsigned short* __restrict__ A,
    const unsigned short* __restrict__ BT,
    const float* __restrict__ bias,
    float* __restrict__ Cf,
    unsigned short* __restrict__ Cx1,
    unsigned short* __restrict__ Cx2,
    int M, int K)
{
  __shared__ unsigned short Als[128*GK];   // 16 KB
  __shared__ unsigned short Bls[128*GK];   // 16 KB
  int tid = threadIdx.x;
  int lane = tid & 63, wave = tid >> 6;
  int wm = (wave >> 1) * 64, wn = (wave & 1) * 64;
  // grid transposed: x = col-blocks (fastest) so the blocks sharing an A-panel
  // dispatch adjacently -> A panel stays L2-resident.
  int row0 = blockIdx.y * 128, col0 = blockIdx.x * 128;

  f32x4 acc[4][4];
#pragma unroll
  for (int i=0;i<4;++i)
#pragma unroll
    for (int j=0;j<4;++j){ acc[i][j].x=0.f; acc[i][j].y=0.f; acc[i][j].z=0.f; acc[i][j].w=0.f; }

  int fm = lane & 15;
  int q4 = lane >> 4;          // quarter-wave index 0..3

  for (int k0 = 0; k0 < K; k0 += GK) {
#pragma unroll
    for (int it = 0; it < 4; ++it) {
      int cgl = it*256 + tid;            // chunk id 0..1023 (16B chunks)
      int r = cgl >> 3;                  // tile row 0..127
      int kb = ((cgl ^ r) & 7) * 8;      // swizzled k-chunk (elements)
      gload_lds16(A  + (size_t)(row0 + r)*K + k0 + kb, Als + (it*256 + wave*64)*8);
      gload_lds16(BT + (size_t)(col0 + r)*K + k0 + kb, Bls + (it*256 + wave*64)*8);
    }
    __syncthreads();

#pragma unroll
    for (int kk = 0; kk < 2; ++kk) {
      int j = kk*4 + q4;                 // logical 16B chunk within row
      bf16x8 af[4], bfr[4];
#pragma unroll
      for (int mi=0; mi<4; ++mi){
        int row = wm + mi*16 + fm;
        af[mi] = *(const bf16x8*)&Als[row*GK + ((j ^ row) & 7)*8];
      }
#pragma unroll
      for (int ni=0; ni<4; ++ni){
        int row = wn + ni*16 + fm;
        bfr[ni] = *(const bf16x8*)&Bls[row*GK + ((j ^ row) & 7)*8];
      }
#pragma unroll
      for (int mi=0; mi<4; ++mi)
#pragma unroll
        for (int ni=0; ni<4; ++ni)
          acc[mi][ni] = __builtin_amdgcn_mfma_f32_16x16x32_bf16(af[mi], bfr[ni], acc[mi][ni], 0, 0, 0);
    }
    __syncthreads();
  }

  int seg = col0 >> 8;
  int colbase = col0 - seg*256;
  int cn = lane & 15, cr = (lane >> 4) * 4;
#pragma unroll
  for (int ni=0; ni<4; ++ni){
    int gcol = col0 + wn + ni*16 + cn;
    int col  = colbase + wn + ni*16 + cn;
    float bb = bias[gcol];
#pragma unroll
    for (int mi=0; mi<4; ++mi){
#pragma unroll
      for (int r=0; r<4; ++r){
        int row = row0 + wm + mi*16 + cr + r;
        if (row < M){
          float v = acc[mi][ni][r] + bb;
          if (seg == 0)      Cf [(size_t)row*256 + col] = v;
          else if (seg == 1) Cx1[(size_t)row*256 + col] = f2b(v);
          else               Cx2[(size_t)row*256 + col] = f2b(v);
        }
      }
    }
  }
}

// ---------------- CSR build by dst ----------------
__global__ void hist_kernel(const int* __restrict__ ei, int* __restrict__ deg){
  int e = blockIdx.x*blockDim.x + threadIdx.x;
  if (e < EE) atomicAdd(&deg[ei[EE + e]], 1);
}

// parallel 3-phase scan
__global__ __launch_bounds__(1024) void scan1_kernel(const int* __restrict__ deg,
                                                     int* __restrict__ incl, int* __restrict__ bsum){
  __shared__ int wsums[16];
  int t = threadIdx.x, lane = t & 63, w = t >> 6;
  int i = blockIdx.x*1024 + t;
  int v = (i < NN) ? deg[i] : 0;
  int sc = v;
#pragma unroll
  for (int off = 1; off < 64; off <<= 1) {
    int o = __shfl_up(sc, off, 64);
    if (lane >= off) sc += o;
  }
  if (lane == 63) wsums[w] = sc;
  __syncthreads();
  if (w == 0) {
    int ws = (lane < 16) ? wsums[lane] : 0;
#pragma unroll
    for (int off = 1; off < 16; off <<= 1) {
      int o = __shfl_up(ws, off, 64);
      if (lane >= off) ws += o;
    }
    if (lane < 16) wsums[lane] = ws;
  }
  __syncthreads();
  int woff = (w > 0) ? wsums[w-1] : 0;
  if (i < NN) incl[i] = sc + woff;
  if (t == 1023) bsum[blockIdx.x] = woff + sc;
}

__global__ void scan2_kernel(int* __restrict__ bsum, int nblk){
  int lane = threadIdx.x;
  int v = (lane < nblk) ? bsum[lane] : 0;
#pragma unroll
  for (int off = 1; off < 64; off <<= 1) {
    int o = __shfl_up(v, off, 64);
    if (lane >= off) v += o;
  }
  if (lane < nblk) bsum[lane] = v;
}

__global__ __launch_bounds__(1024) void scan3_kernel(const int* __restrict__ incl,
                                                     const int* __restrict__ deg,
                                                     const int* __restrict__ bsum,
                                                     int* __restrict__ rowptr, int* __restrict__ cursor,
                                                     int nblk){
  int i = blockIdx.x*1024 + threadIdx.x;
  if (i < NN) {
    int b = blockIdx.x;
    int prev = (b > 0) ? bsum[b-1] : 0;
    int ex = prev + incl[i] - deg[i];
    rowptr[i] = ex;
    cursor[i] = ex;
  }
  if (i == 0) rowptr[NN] = bsum[nblk-1];
}

// scatter: place edge into its dst bin AND precompute edge geometry
__global__ void scatter_kernel(const int* __restrict__ ei, const float* __restrict__ kpts,
                               int* __restrict__ cursor,
                               float4* __restrict__ edata, int* __restrict__ eord){
  int e = blockIdx.x*blockDim.x + threadIdx.x;
  if (e >= EE) return;
  int s = ei[e];
  int d = ei[EE + e];
  int pos = atomicAdd(&cursor[d], 1);
  float su = kpts[2*s]   * (1.0f/1216.0f);
  float sv = kpts[2*s+1] * (1.0f/352.0f);
  float du = kpts[2*d]   * (1.0f/1216.0f);
  float dv = kpts[2*d+1] * (1.0f/352.0f);
  float ru = du - su, rv = dv - sv;
  float dist = sqrtf(ru*ru + rv*rv);
  float4 ed; ed.x = ru; ed.y = rv; ed.z = dist; ed.w = __int_as_float(s);
  edata[pos] = ed;
  eord[pos] = e;
}

// ---------------- per-node attention: batched 8-deep gather pipeline + packed fp32 ----------------
// (round-0 structure: 1 wave per node, 64 lanes x 4 channels, readlane-broadcast
//  edge scalars, 8-deep flat gather pipeline. 48 VGPR -> 8 waves/SIMD.)
#define LOAD8(Q, B0)                                               \
  if ((B0) < cnt) {                                                \
    _Pragma("unroll")                                              \
    for (int t = 0; t < 8; ++t) {                                  \
      int sj = rlane_i(s, ((B0) + t) & 63);                        \
      Q[t] = *(const uint2*)(xlp + ((size_t)sj << 8));             \
    }                                                              \
  }

#define PROC8(Q, B0)                                               \
  _Pragma("unroll")                                                \
  for (int t = 0; t < 8; ++t) {                                    \
    int j = (B0) + t;                                              \
    if (j < cnt) {                                                 \
      float ruj = rlane_f(ed.x, j);                                \
      float rvj = rlane_f(ed.y, j);                                \
      float dj  = rlane_f(ed.z, j);                                \
      f32x2 x01 = unpk(Q[t].x), x23 = unpk(Q[t].y);                \
      f32x2 t01 = fma2(set2(ruj), we0a, xr01);                     \
      t01 = fma2(set2(rvj), we1a, t01);                            \
      t01 = fma2(set2(dj),  we2a, t01);                            \
      t01 = t01 + x01;                                             \
      f32x2 t23 = fma2(set2(ruj), we0b, xr23);                     \
      t23 = fma2(set2(rvj), we1b, t23);                            \
      t23 = fma2(set2(dj),  we2b, t23);                            \
      t23 = t23 + x23;                                             \
      t01 = max2(t01, t01*0.2f);                                   \
      t23 = max2(t23, t23*0.2f);                                   \
      f32x2 pd = t01*atta;                                         \
      pd = fma2(t23, attb, pd);                                    \
      float p = pd.x + pd.y;                                       \
      p += __shfl_xor(p, 1, 64);                                   \
      p += __shfl_xor(p, 2, 64);                                   \
      p += __shfl_xor(p, 4, 64);                                   \
      p += __shfl_xor(p, 8, 64);                                   \
      float exv = __expf(p);                                       \
      denom += exv;                                                \
      int ej = rlane_i(e, j);                                      \
      if ((lane & 15) == 0) alpha_out[(size_t)ej*4 + head] = exv;  \
      f32x2 ex2 = set2(exv);                                       \
      agg01 = fma2(ex2, x01, agg01);                               \
      agg23 = fma2(ex2, x23, agg23);                               \
    }                                                              \
  }

__global__ __launch_bounds__(128) void node_attn_kernel(
    const float4* __restrict__ edata, const int* __restrict__ eord,
    const unsigned short* __restrict__ xl, const unsigned short* __restrict__ xr,
    const float* __restrict__ We, const float* __restrict__ att,
    const float* __restrict__ cbias, const float* __restrict__ gamma,
    const float* __restrict__ beta,
    const int* __restrict__ rowptr,
    const float* __restrict__ identity,
    float* __restrict__ alpha_out, float* __restrict__ denom_buf,
    unsigned short* __restrict__ hbuf)
{
  int wid  = threadIdx.x >> 6;
  int lane = threadIdx.x & 63;
  int v = blockIdx.x*2 + wid;
  if (v >= NN) return;
  int c0 = lane*4;
  int head = lane >> 4;

  f32x2 we0a, we0b, we1a, we1b, we2a, we2b, atta, attb;
  we0a.x = We[c0];       we0a.y = We[c0+1];       we0b.x = We[c0+2];       we0b.y = We[c0+3];
  we1a.x = We[256+c0];   we1a.y = We[256+c0+1];   we1b.x = We[256+c0+2];   we1b.y = We[256+c0+3];
  we2a.x = We[512+c0];   we2a.y = We[512+c0+1];   we2b.x = We[512+c0+2];   we2b.y = We[512+c0+3];
  atta.x = att[c0];      atta.y = att[c0+1];      attb.x = att[c0+2];      attb.y = att[c0+3];
  uint2 xrq = *(const uint2*)(xr + (size_t)v*256 + c0);
  f32x2 xr01 = unpk(xrq.x), xr23 = unpk(xrq.y);
  const unsigned short* xlp = xl + c0;

  int rs = rowptr[v], re = rowptr[v+1];
  int deg = re - rs;

  float denom = 0.f;
  f32x2 agg01 = set2(0.f), agg23 = set2(0.f);

  for (int base = 0; base < deg; base += 64) {
    int cnt = min(64, deg - base);
    float4 ed; ed.x = 0.f; ed.y = 0.f; ed.z = 0.f; ed.w = __int_as_float(0);
    int e = 0;
    if (lane < cnt) {
      ed = edata[rs + base + lane];
      e  = eord [rs + base + lane];
    }
    int s = __float_as_int(ed.w);

    uint2 qa[8], qb[8];
    LOAD8(qa, 0);
    for (int b0 = 0; b0 < cnt; b0 += 16) {
      LOAD8(qb, b0 + 8);
      PROC8(qa, b0);
      LOAD8(qa, b0 + 16);
      PROC8(qb, b0 + 8);
    }
  }

  float rdenom = 1.0f / (denom + 1e-16f);
  if ((lane & 15) == 0) denom_buf[(size_t)v*4 + head] = denom;

  float a0 = agg01.x*rdenom + cbias[c0];
  float a1 = agg01.y*rdenom + cbias[c0+1];
  float a2 = agg23.x*rdenom + cbias[c0+2];
  float a3 = agg23.y*rdenom + cbias[c0+3];

  float ps  = a0 + a1 + a2 + a3;
  float ps2 = a0*a0 + a1*a1 + a2*a2 + a3*a3;
#pragma unroll
  for (int off = 1; off < 64; off <<= 1) {
    ps  += __shfl_xor(ps,  off, 64);
    ps2 += __shfl_xor(ps2, off, 64);
  }
  float mu  = ps  * (1.0f/256.0f);
  float var = ps2 * (1.0f/256.0f) - mu*mu;
  float rstd = rsqrtf(var + 1e-5f);
  float4 g  = ld4(gamma + c0);
  float4 b  = ld4(beta  + c0);
  float4 idv = ld4(identity + (size_t)v*256 + c0);
  float y0 = (a0 - mu)*rstd*g.x + b.x;
  float y1 = (a1 - mu)*rstd*g.y + b.y;
  float y2 = (a2 - mu)*rstd*g.z + b.z;
  float y3 = (a3 - mu)*rstd*g.w + b.w;
  y0 = y0 / (1.0f + __expf(-y0)) + idv.x;
  y1 = y1 / (1.0f + __expf(-y1)) + idv.y;
  y2 = y2 / (1.0f + __expf(-y2)) + idv.z;
  y3 = y3 / (1.0f + __expf(-y3)) + idv.w;
  ushort4 hq; hq.x=f2b(y0); hq.y=f2b(y1); hq.z=f2b(y2); hq.w=f2b(y3);
  *(ushort4*)(hbuf + (size_t)v*256 + c0) = hq;
}

// ---------------- finalize alpha: alpha[e,h] = ex[e,h] / (denom[dst,h]+1e-16) ----------------
__global__ void alpha_fin_kernel(const int* __restrict__ ei, const float* __restrict__ denom_buf,
                                 float* __restrict__ alpha)
{
  int e = blockIdx.x*blockDim.x + threadIdx.x;
  if (e >= EE) return;
  int d = ei[EE + e];
  float4 dn = ld4(denom_buf + (size_t)d*4);
  float4 a = ld4(alpha + (size_t)e*4);
  a.x /= (dn.x + 1e-16f);
  a.y /= (dn.y + 1e-16f);
  a.z /= (dn.z + 1e-16f);
  a.w /= (dn.w + 1e-16f);
  *(float4*)(alpha + (size_t)e*4) = a;
}

extern "C" void kernel_launch(void* const* d_in, const int* in_sizes, int n_in,
                              void* d_out, int out_size, void* d_ws, size_t ws_size,
                              hipStream_t stream)
{
  const float* x      = (const float*)d_in[0];
  const float* kpts   = (const float*)d_in[1];
  const float* pts3d  = (const float*)d_in[2];
  const int*   ei     = (const int*)d_in[3];
  const float* W1     = (const float*)d_in[4];
  const float* b1     = (const float*)d_in[5];
  const float* W2     = (const float*)d_in[6];
  const float* b2     = (const float*)d_in[7];
  const float* Wres   = (const float*)d_in[8];
  const float* bres   = (const float*)d_in[9];
  const float* Wl     = (const float*)d_in[10];
  const float* bl     = (const float*)d_in[11];
  const float* Wr     = (const float*)d_in[12];
  const float* br     = (const float*)d_in[13];
  const float* We     = (const float*)d_in[14];
  const float* att    = (const float*)d_in[15];
  const float* cbias  = (const float*)d_in[16];
  const float* gamma  = (const float*)d_in[17];
  const float* beta   = (const float*)d_in[18];
  const float* Wp     = (const float*)d_in[19];
  const float* bp     = (const float*)d_in[20];

  float* out       = (float*)d_out;
  float* alpha_out = out + (size_t)NN*HIDC;

  // workspace layout (units: float elements) — ~153 MB
  float* wsf = (float*)d_ws;
  float*          identity = wsf;                               // 12,800,000 f
  unsigned short* xl       = (unsigned short*)(wsf + 12800000); // 12,812,288 us
  unsigned short* xr       = (unsigned short*)(wsf + 19206144);
  unsigned short* nodex    = (unsigned short*)(wsf + 25612288); // 16,015,360 us
  unsigned short* hbuf     = (unsigned short*)(wsf + 25612288); // alias nodex (dead after gemm3)
  unsigned short* wt       = (unsigned short*)(wsf + 33619968); // 311,296 us
  float*          biascat  = wsf + 33775616;                    // 768 f
  float*          denomb   = wsf + 33776384;                    // 200,000 f
  float4*         edata    = (float4*)(wsf + 33976384);         // 800,000 float4
  int*            eord     = (int*)(wsf + 37176384);            // 800,000 i
  int*            incl     = (int*)(wsf + 37176384);            // alias eord (dead before scatter)
  int*            deg      = (int*)(wsf + 37976384);            // 50,000 i
  int*            rowptr   = (int*)(wsf + 38026384);            // 50,001 i
  int*            cursor   = (int*)(wsf + 38076385);            // 50,000 i
  int*            bsum     = (int*)(wsf + 38126385);            // 64 i

  unsigned short* wtcat = wt;            // 768 x 320 (Wres_T | Wl_T | Wr_T)
  unsigned short* wtp   = wt + 245760;   // 256 x 256

  cvt_x_kernel<<<12500, 256, 0, stream>>>(x, nodex);
  node_mlp_kernel<<<(NN+255)/256, 256, 0, stream>>>(kpts, pts3d, W1, b1, W2, b2, nodex);
  cvt_w_kernel<<<1219, 256, 0, stream>>>(Wres, Wl, Wr, Wp, bres, bl, br, wt, biascat);

  // fused triple GEMM: [identity | x_l | x_r] = nodex @ [Wres|Wl|Wr] + [bres|bl|br]
  // grid transposed: col-blocks fastest (share the A panel -> L2-resident)
  dim3 g3(6, NPAD/128);
  mfma_gemm_kernel<<<g3, 256, 0, stream>>>(nodex, wtcat, biascat, identity, xl, xr, NN, INCH);

  hipMemsetAsync(deg, 0, NN*sizeof(int), stream);
  hist_kernel<<<(EE+255)/256, 256, 0, stream>>>(ei, deg);
  int nblk = (NN + 1023) / 1024;   // 49
  scan1_kernel<<<nblk, 1024, 0, stream>>>(deg, incl, bsum);
  scan2_kernel<<<1, 64, 0, stream>>>(bsum, nblk);
  scan3_kernel<<<nblk, 1024, 0, stream>>>(incl, deg, bsum, rowptr, cursor, nblk);
  scatter_kernel<<<(EE+255)/256, 256, 0, stream>>>(ei, kpts, cursor, edata, eord);

  node_attn_kernel<<<(NN+1)/2, 128, 0, stream>>>(edata, eord, xl, xr, We, att,
                                                 cbias, gamma, beta,
                                                 rowptr, identity,
                                                 alpha_out, denomb, hbuf);
  alpha_fin_kernel<<<(EE+255)/256, 256, 0, stream>>>(ei, denomb, alpha_out);

  dim3 g1(2, NPAD/128);
  mfma_gemm_kernel<<<g1, 256, 0, stream>>>(hbuf, wtp, bp, out, nullptr, nullptr, NN, HIDC);
}

// Round 5
// 536.985 us; speedup vs baseline: 1.2010x; 1.0058x over previous
//
#include <hip/hip_runtime.h>
#include <math.h>

#define NN 50000
#define NPAD 50048
#define EE 800000
#define HIDC 256
#define INCH 320

typedef __attribute__((ext_vector_type(8))) short bf16x8;
typedef __attribute__((ext_vector_type(4))) float f32x4;
typedef __attribute__((ext_vector_type(2))) float f32x2;

static __device__ __forceinline__ float4 ld4(const float* p){ return *(const float4*)p; }

static __device__ __forceinline__ unsigned short f2b(float f){
  union { float f; unsigned u; } v; v.f = f;
  unsigned r = v.u + 0x7fffu + ((v.u >> 16) & 1u);
  return (unsigned short)(r >> 16);
}
static __device__ __forceinline__ float b2f(unsigned short u){
  union { unsigned u; float f; } v; v.u = ((unsigned)u) << 16; return v.f;
}
static __device__ __forceinline__ float rlane_f(float v, int l){
  return __uint_as_float(__builtin_amdgcn_readlane(__float_as_uint(v), l));
}
static __device__ __forceinline__ int rlane_i(int v, int l){
  return __builtin_amdgcn_readlane(v, l);
}
// unpack two bf16 packed in a u32 -> 2 floats (lo = .x, hi = .y)
static __device__ __forceinline__ f32x2 unpk(unsigned u){
  f32x2 r;
  r.x = __uint_as_float(u << 16);
  r.y = __uint_as_float(u & 0xffff0000u);
  return r;
}
static __device__ __forceinline__ f32x2 fma2(f32x2 a, f32x2 b, f32x2 c){
  return __builtin_elementwise_fma(a, b, c);
}
static __device__ __forceinline__ f32x2 max2(f32x2 a, f32x2 b){
  return __builtin_elementwise_max(a, b);
}
static __device__ __forceinline__ f32x2 set2(float v){ f32x2 r; r.x = v; r.y = v; return r; }

typedef const __attribute__((address_space(1))) unsigned int* gas_u32;
typedef __attribute__((address_space(3))) unsigned int* las_u32;
static __device__ __forceinline__ void gload_lds16(const void* g, void* l){
  __builtin_amdgcn_global_load_lds((gas_u32)g, (las_u32)l, 16, 0, 0);
}

// ---------------- convert x (fp32 50000x256) into node_x bf16 (NPAD x 320, cols 0..255) ----------------
__global__ void cvt_x_kernel(const float* __restrict__ x, unsigned short* __restrict__ nodex)
{
  int t = blockIdx.x*blockDim.x + threadIdx.x;
  int row = t >> 6;
  if (row >= NN) return;
  int c4 = (t & 63) * 4;
  float4 v = ld4(x + (size_t)row*256 + c4);
  ushort4 o;
  o.x = f2b(v.x); o.y = f2b(v.y); o.z = f2b(v.z); o.w = f2b(v.w);
  *(ushort4*)(nodex + (size_t)row*320 + c4) = o;
}

// ---------------- node positional MLP: writes bf16 into node_x cols 256..319 + norm_uv table ----------------
__global__ void node_mlp_kernel(const float* __restrict__ kpts,
                                const float* __restrict__ pts3d,
                                const float* __restrict__ W1, const float* __restrict__ b1,
                                const float* __restrict__ W2, const float* __restrict__ b2,
                                unsigned short* __restrict__ nodex,
                                float* __restrict__ nuv)
{
  int i = blockIdx.x*blockDim.x + threadIdx.x;
  if (i >= NN) return;
  float u = kpts[2*i]   * (1.0f/1216.0f);
  float v = kpts[2*i+1] * (1.0f/352.0f);
  float d = pts3d[3*i+2];
  float2 uv; uv.x = u; uv.y = v;
  *(float2*)(nuv + 2*i) = uv;
  float h[32];
#pragma unroll
  for (int j=0;j<32;++j){
    float t = u*W1[j] + v*W1[32+j] + d*W1[64+j] + b1[j];
    h[j] = t / (1.0f + __expf(-t));   // silu
  }
  for (int o=0;o<64;o+=4){
    float s0=b2[o], s1=b2[o+1], s2=b2[o+2], s3=b2[o+3];
#pragma unroll
    for (int j=0;j<32;++j){
      float hj = h[j];
      const float* w = W2 + j*64 + o;
      s0 += hj*w[0]; s1 += hj*w[1]; s2 += hj*w[2]; s3 += hj*w[3];
    }
    ushort4 r; r.x=f2b(s0); r.y=f2b(s1); r.z=f2b(s2); r.w=f2b(s3);
    *(ushort4*)(nodex + (size_t)i*320 + 256 + o) = r;
  }
}

// ---------------- convert + transpose weights to bf16 N-major (K contiguous) + bias concat ----------------
__global__ void cvt_w_kernel(const float* __restrict__ Wres, const float* __restrict__ Wl,
                             const float* __restrict__ Wr,   const float* __restrict__ Wp,
                             const float* __restrict__ bres, const float* __restrict__ bl,
                             const float* __restrict__ br,
                             unsigned short* __restrict__ wt, float* __restrict__ biascat)
{
  int t = blockIdx.x*blockDim.x + threadIdx.x;   // 312064 threads
  if (t < 245760) {
    int which = t / 81920;
    int rem = t % 81920;
    int n = rem / 320, k = rem % 320;
    const float* W = (which == 0) ? Wres : (which == 1) ? Wl : Wr;
    wt[(size_t)which*81920 + rem] = f2b(W[(size_t)k*256 + n]);
  } else if (t < 311296) {
    int r = t - 245760;
    int n = r / 256, k = r % 256;
    wt[245760 + r] = f2b(Wp[(size_t)k*256 + n]);
  } else {
    int r = t - 311296;   // 0..767
    const float* src = (r < 256) ? bres : (r < 512) ? bl : br;
    biascat[r] = src[r & 255];
  }
}

// ---------------- bf16 MFMA GEMM: C(M,Nt) = A(M,K) @ BT(Nt,K)^T + bias ----------------
// GK=64 + XOR slot-swizzle (see r4 notes); grid transposed (col-blocks fastest).
#define GK 64
__global__ __launch_bounds__(256) void mfma_gemm_kernel(
    const unsigned short* __restrict__ A,
    const unsigned short* __restrict__ BT,
    const float* __restrict__ bias,
    float* __restrict__ Cf,
    unsigned short* __restrict__ Cx1,
    unsigned short* __restrict__ Cx2,
    int M, int K)
{
  __shared__ unsigned short Als[128*GK];   // 16 KB
  __shared__ unsigned short Bls[128*GK];   // 16 KB
  int tid = threadIdx.x;
  int lane = tid & 63, wave = tid >> 6;
  int wm = (wave >> 1) * 64, wn = (wave & 1) * 64;
  int row0 = blockIdx.y * 128, col0 = blockIdx.x * 128;

  f32x4 acc[4][4];
#pragma unroll
  for (int i=0;i<4;++i)
#pragma unroll
    for (int j=0;j<4;++j){ acc[i][j].x=0.f; acc[i][j].y=0.f; acc[i][j].z=0.f; acc[i][j].w=0.f; }

  int fm = lane & 15;
  int q4 = lane >> 4;          // quarter-wave index 0..3

  for (int k0 = 0; k0 < K; k0 += GK) {
#pragma unroll
    for (int it = 0; it < 4; ++it) {
      int cgl = it*256 + tid;            // chunk id 0..1023 (16B chunks)
      int r = cgl >> 3;                  // tile row 0..127
      int kb = ((cgl ^ r) & 7) * 8;      // swizzled k-chunk (elements)
      gload_lds16(A  + (size_t)(row0 + r)*K + k0 + kb, Als + (it*256 + wave*64)*8);
      gload_lds16(BT + (size_t)(col0 + r)*K + k0 + kb, Bls + (it*256 + wave*64)*8);
    }
    __syncthreads();

#pragma unroll
    for (int kk = 0; kk < 2; ++kk) {
      int j = kk*4 + q4;                 // logical 16B chunk within row
      bf16x8 af[4], bfr[4];
#pragma unroll
      for (int mi=0; mi<4; ++mi){
        int row = wm + mi*16 + fm;
        af[mi] = *(const bf16x8*)&Als[row*GK + ((j ^ row) & 7)*8];
      }
#pragma unroll
      for (int ni=0; ni<4; ++ni){
        int row = wn + ni*16 + fm;
        bfr[ni] = *(const bf16x8*)&Bls[row*GK + ((j ^ row) & 7)*8];
      }
#pragma unroll
      for (int mi=0; mi<4; ++mi)
#pragma unroll
        for (int ni=0; ni<4; ++ni)
          acc[mi][ni] = __builtin_amdgcn_mfma_f32_16x16x32_bf16(af[mi], bfr[ni], acc[mi][ni], 0, 0, 0);
    }
    __syncthreads();
  }

  int seg = col0 >> 8;
  int colbase = col0 - seg*256;
  int cn = lane & 15, cr = (lane >> 4) * 4;
#pragma unroll
  for (int ni=0; ni<4; ++ni){
    int gcol = col0 + wn + ni*16 + cn;
    int col  = colbase + wn + ni*16 + cn;
    float bb = bias[gcol];
#pragma unroll
    for (int mi=0; mi<4; ++mi){
#pragma unroll
      for (int r=0; r<4; ++r){
        int row = row0 + wm + mi*16 + cr + r;
        if (row < M){
          float v = acc[mi][ni][r] + bb;
          if (seg == 0)      Cf [(size_t)row*256 + col] = v;
          else if (seg == 1) Cx1[(size_t)row*256 + col] = f2b(v);
          else               Cx2[(size_t)row*256 + col] = f2b(v);
        }
      }
    }
  }
}

// ---------------- CSR build by dst ----------------
__global__ void hist_kernel(const int* __restrict__ ei, int* __restrict__ deg){
  int e = blockIdx.x*blockDim.x + threadIdx.x;
  if (e < EE) atomicAdd(&deg[ei[EE + e]], 1);
}

// parallel 3-phase scan
__global__ __launch_bounds__(1024) void scan1_kernel(const int* __restrict__ deg,
                                                     int* __restrict__ incl, int* __restrict__ bsum){
  __shared__ int wsums[16];
  int t = threadIdx.x, lane = t & 63, w = t >> 6;
  int i = blockIdx.x*1024 + t;
  int v = (i < NN) ? deg[i] : 0;
  int sc = v;
#pragma unroll
  for (int off = 1; off < 64; off <<= 1) {
    int o = __shfl_up(sc, off, 64);
    if (lane >= off) sc += o;
  }
  if (lane == 63) wsums[w] = sc;
  __syncthreads();
  if (w == 0) {
    int ws = (lane < 16) ? wsums[lane] : 0;
#pragma unroll
    for (int off = 1; off < 16; off <<= 1) {
      int o = __shfl_up(ws, off, 64);
      if (lane >= off) ws += o;
    }
    if (lane < 16) wsums[lane] = ws;
  }
  __syncthreads();
  int woff = (w > 0) ? wsums[w-1] : 0;
  if (i < NN) incl[i] = sc + woff;
  if (t == 1023) bsum[blockIdx.x] = woff + sc;
}

__global__ void scan2_kernel(int* __restrict__ bsum, int nblk){
  int lane = threadIdx.x;
  int v = (lane < nblk) ? bsum[lane] : 0;
#pragma unroll
  for (int off = 1; off < 64; off <<= 1) {
    int o = __shfl_up(v, off, 64);
    if (lane >= off) v += o;
  }
  if (lane < nblk) bsum[lane] = v;
}

__global__ __launch_bounds__(1024) void scan3_kernel(const int* __restrict__ incl,
                                                     const int* __restrict__ deg,
                                                     const int* __restrict__ bsum,
                                                     int* __restrict__ rowptr, int* __restrict__ cursor,
                                                     int nblk){
  int i = blockIdx.x*1024 + threadIdx.x;
  if (i < NN) {
    int b = blockIdx.x;
    int prev = (b > 0) ? bsum[b-1] : 0;
    int ex = prev + incl[i] - deg[i];
    rowptr[i] = ex;
    cursor[i] = ex;
  }
  if (i == 0) rowptr[NN] = bsum[nblk-1];
}

// scatter: place edge into its dst bin. Only 8B per edge ({src, edge_id}) —
// geometry is recomputed in attn from the norm_uv table (bit-identical math).
__global__ void scatter_kernel(const int* __restrict__ ei,
                               int* __restrict__ cursor,
                               uint2* __restrict__ sedata){
  int e = blockIdx.x*blockDim.x + threadIdx.x;
  if (e >= EE) return;
  int s = ei[e];
  int d = ei[EE + e];
  int pos = atomicAdd(&cursor[d], 1);
  uint2 se; se.x = (unsigned)s; se.y = (unsigned)e;
  sedata[pos] = se;
}

// ---------------- per-node attention: batched 8-deep gather pipeline + packed fp32 ----------------
// (1 wave per node, 64 lanes x 4 channels, readlane-broadcast edge scalars,
//  8-deep flat gather pipeline. Edge geometry recomputed in the chunk header
//  from norm_uv[s] (L2-resident 400 KB) + wave-uniform norm_uv[v].)
#define LOAD8(Q, B0)                                               \
  if ((B0) < cnt) {                                                \
    _Pragma("unroll")                                              \
    for (int t = 0; t < 8; ++t) {                                  \
      int sj = rlane_i(s, ((B0) + t) & 63);                        \
      Q[t] = *(const uint2*)(xlp + ((size_t)sj << 8));             \
    }                                                              \
  }

#define PROC8(Q, B0)                                               \
  _Pragma("unroll")                                                \
  for (int t = 0; t < 8; ++t) {                                    \
    int j = (B0) + t;                                              \
    if (j < cnt) {                                                 \
      float ruj = rlane_f(edx, j);                                 \
      float rvj = rlane_f(edy, j);                                 \
      float dj  = rlane_f(edz, j);                                 \
      f32x2 x01 = unpk(Q[t].x), x23 = unpk(Q[t].y);                \
      f32x2 t01 = fma2(set2(ruj), we0a, xr01);                     \
      t01 = fma2(set2(rvj), we1a, t01);                            \
      t01 = fma2(set2(dj),  we2a, t01);                            \
      t01 = t01 + x01;                                             \
      f32x2 t23 = fma2(set2(ruj), we0b, xr23);                     \
      t23 = fma2(set2(rvj), we1b, t23);                            \
      t23 = fma2(set2(dj),  we2b, t23);                            \
      t23 = t23 + x23;                                             \
      t01 = max2(t01, t01*0.2f);                                   \
      t23 = max2(t23, t23*0.2f);                                   \
      f32x2 pd = t01*atta;                                         \
      pd = fma2(t23, attb, pd);                                    \
      float p = pd.x + pd.y;                                       \
      p += __shfl_xor(p, 1, 64);                                   \
      p += __shfl_xor(p, 2, 64);                                   \
      p += __shfl_xor(p, 4, 64);                                   \
      p += __shfl_xor(p, 8, 64);                                   \
      float exv = __expf(p);                                       \
      denom += exv;                                                \
      int ej = rlane_i(e, j);                                      \
      if ((lane & 15) == 0) alpha_out[(size_t)ej*4 + head] = exv;  \
      f32x2 ex2 = set2(exv);                                       \
      agg01 = fma2(ex2, x01, agg01);                               \
      agg23 = fma2(ex2, x23, agg23);                               \
    }                                                              \
  }

__global__ __launch_bounds__(128) void node_attn_kernel(
    const uint2* __restrict__ sedata, const float* __restrict__ nuv,
    const unsigned short* __restrict__ xl, const unsigned short* __restrict__ xr,
    const float* __restrict__ We, const float* __restrict__ att,
    const float* __restrict__ cbias, const float* __restrict__ gamma,
    const float* __restrict__ beta,
    const int* __restrict__ rowptr,
    const float* __restrict__ identity,
    float* __restrict__ alpha_out, float* __restrict__ denom_buf,
    unsigned short* __restrict__ hbuf)
{
  int wid  = threadIdx.x >> 6;
  int lane = threadIdx.x & 63;
  int v = blockIdx.x*2 + wid;
  if (v >= NN) return;
  int c0 = lane*4;
  int head = lane >> 4;

  f32x2 we0a, we0b, we1a, we1b, we2a, we2b, atta, attb;
  we0a.x = We[c0];       we0a.y = We[c0+1];       we0b.x = We[c0+2];       we0b.y = We[c0+3];
  we1a.x = We[256+c0];   we1a.y = We[256+c0+1];   we1b.x = We[256+c0+2];   we1b.y = We[256+c0+3];
  we2a.x = We[512+c0];   we2a.y = We[512+c0+1];   we2b.x = We[512+c0+2];   we2b.y = We[512+c0+3];
  atta.x = att[c0];      atta.y = att[c0+1];      attb.x = att[c0+2];      attb.y = att[c0+3];
  uint2 xrq = *(const uint2*)(xr + (size_t)v*256 + c0);
  f32x2 xr01 = unpk(xrq.x), xr23 = unpk(xrq.y);
  const unsigned short* xlp = xl + c0;
  float2 duv = *(const float2*)(nuv + 2*(size_t)v);

  int rs = rowptr[v], re = rowptr[v+1];
  int deg = re - rs;

  float denom = 0.f;
  f32x2 agg01 = set2(0.f), agg23 = set2(0.f);

  for (int base = 0; base < deg; base += 64) {
    int cnt = min(64, deg - base);
    int s = 0, e = 0;
    if (lane < cnt) {
      uint2 se = sedata[rs + base + lane];
      s = (int)se.x;
      e = (int)se.y;
    }
    // recompute geometry (bit-identical to the old scatter-side math)
    float2 suv = *(const float2*)(nuv + 2*(size_t)s);
    float edx = duv.x - suv.x;
    float edy = duv.y - suv.y;
    float edz = sqrtf(edx*edx + edy*edy);

    uint2 qa[8], qb[8];
    LOAD8(qa, 0);
    for (int b0 = 0; b0 < cnt; b0 += 16) {
      LOAD8(qb, b0 + 8);
      PROC8(qa, b0);
      LOAD8(qa, b0 + 16);
      PROC8(qb, b0 + 8);
    }
  }

  float rdenom = 1.0f / (denom + 1e-16f);
  if ((lane & 15) == 0) denom_buf[(size_t)v*4 + head] = denom;

  float a0 = agg01.x*rdenom + cbias[c0];
  float a1 = agg01.y*rdenom + cbias[c0+1];
  float a2 = agg23.x*rdenom + cbias[c0+2];
  float a3 = agg23.y*rdenom + cbias[c0+3];

  float ps  = a0 + a1 + a2 + a3;
  float ps2 = a0*a0 + a1*a1 + a2*a2 + a3*a3;
#pragma unroll
  for (int off = 1; off < 64; off <<= 1) {
    ps  += __shfl_xor(ps,  off, 64);
    ps2 += __shfl_xor(ps2, off, 64);
  }
  float mu  = ps  * (1.0f/256.0f);
  float var = ps2 * (1.0f/256.0f) - mu*mu;
  float rstd = rsqrtf(var + 1e-5f);
  float4 g  = ld4(gamma + c0);
  float4 b  = ld4(beta  + c0);
  float4 idv = ld4(identity + (size_t)v*256 + c0);
  float y0 = (a0 - mu)*rstd*g.x + b.x;
  float y1 = (a1 - mu)*rstd*g.y + b.y;
  float y2 = (a2 - mu)*rstd*g.z + b.z;
  float y3 = (a3 - mu)*rstd*g.w + b.w;
  y0 = y0 / (1.0f + __expf(-y0)) + idv.x;
  y1 = y1 / (1.0f + __expf(-y1)) + idv.y;
  y2 = y2 / (1.0f + __expf(-y2)) + idv.z;
  y3 = y3 / (1.0f + __expf(-y3)) + idv.w;
  ushort4 hq; hq.x=f2b(y0); hq.y=f2b(y1); hq.z=f2b(y2); hq.w=f2b(y3);
  *(ushort4*)(hbuf + (size_t)v*256 + c0) = hq;
}

// ---------------- finalize alpha: alpha[e,h] = ex[e,h] / (denom[dst,h]+1e-16) ----------------
__global__ void alpha_fin_kernel(const int* __restrict__ ei, const float* __restrict__ denom_buf,
                                 float* __restrict__ alpha)
{
  int e = blockIdx.x*blockDim.x + threadIdx.x;
  if (e >= EE) return;
  int d = ei[EE + e];
  float4 dn = ld4(denom_buf + (size_t)d*4);
  float4 a = ld4(alpha + (size_t)e*4);
  a.x /= (dn.x + 1e-16f);
  a.y /= (dn.y + 1e-16f);
  a.z /= (dn.z + 1e-16f);
  a.w /= (dn.w + 1e-16f);
  *(float4*)(alpha + (size_t)e*4) = a;
}

extern "C" void kernel_launch(void* const* d_in, const int* in_sizes, int n_in,
                              void* d_out, int out_size, void* d_ws, size_t ws_size,
                              hipStream_t stream)
{
  const float* x      = (const float*)d_in[0];
  const float* kpts   = (const float*)d_in[1];
  const float* pts3d  = (const float*)d_in[2];
  const int*   ei     = (const int*)d_in[3];
  const float* W1     = (const float*)d_in[4];
  const float* b1     = (const float*)d_in[5];
  const float* W2     = (const float*)d_in[6];
  const float* b2     = (const float*)d_in[7];
  const float* Wres   = (const float*)d_in[8];
  const float* bres   = (const float*)d_in[9];
  const float* Wl     = (const float*)d_in[10];
  const float* bl     = (const float*)d_in[11];
  const float* Wr     = (const float*)d_in[12];
  const float* br     = (const float*)d_in[13];
  const float* We     = (const float*)d_in[14];
  const float* att    = (const float*)d_in[15];
  const float* cbias  = (const float*)d_in[16];
  const float* gamma  = (const float*)d_in[17];
  const float* beta   = (const float*)d_in[18];
  const float* Wp     = (const float*)d_in[19];
  const float* bp     = (const float*)d_in[20];

  float* out       = (float*)d_out;
  float* alpha_out = out + (size_t)NN*HIDC;

  // workspace layout (units: float elements) — ~153 MB
  float* wsf = (float*)d_ws;
  float*          identity = wsf;                               // 12,800,000 f
  unsigned short* xl       = (unsigned short*)(wsf + 12800000); // 12,812,288 us
  unsigned short* xr       = (unsigned short*)(wsf + 19206144);
  unsigned short* nodex    = (unsigned short*)(wsf + 25612288); // 16,015,360 us
  unsigned short* hbuf     = (unsigned short*)(wsf + 25612288); // alias nodex (dead after gemm3)
  unsigned short* wt       = (unsigned short*)(wsf + 33619968); // 311,296 us
  float*          biascat  = wsf + 33775616;                    // 768 f
  float*          denomb   = wsf + 33776384;                    // 200,000 f
  uint2*          sedata   = (uint2*)(wsf + 33976384);          // 800,000 uint2 (1.6M f)
  float*          nuv      = wsf + 35576384;                    // 100,000 f (norm_uv)
  int*            incl     = (int*)(wsf + 37176384);            // 800,000 i scratch
  int*            deg      = (int*)(wsf + 37976384);            // 50,000 i
  int*            rowptr   = (int*)(wsf + 38026384);            // 50,001 i
  int*            cursor   = (int*)(wsf + 38076385);            // 50,000 i
  int*            bsum     = (int*)(wsf + 38126385);            // 64 i

  unsigned short* wtcat = wt;            // 768 x 320 (Wres_T | Wl_T | Wr_T)
  unsigned short* wtp   = wt + 245760;   // 256 x 256

  cvt_x_kernel<<<12500, 256, 0, stream>>>(x, nodex);
  node_mlp_kernel<<<(NN+255)/256, 256, 0, stream>>>(kpts, pts3d, W1, b1, W2, b2, nodex, nuv);
  cvt_w_kernel<<<1219, 256, 0, stream>>>(Wres, Wl, Wr, Wp, bres, bl, br, wt, biascat);

  // fused triple GEMM: [identity | x_l | x_r] = nodex @ [Wres|Wl|Wr] + [bres|bl|br]
  // grid transposed: col-blocks fastest (share the A panel -> L2-resident)
  dim3 g3(6, NPAD/128);
  mfma_gemm_kernel<<<g3, 256, 0, stream>>>(nodex, wtcat, biascat, identity, xl, xr, NN, INCH);

  hipMemsetAsync(deg, 0, NN*sizeof(int), stream);
  hist_kernel<<<(EE+255)/256, 256, 0, stream>>>(ei, deg);
  int nblk = (NN + 1023) / 1024;   // 49
  scan1_kernel<<<nblk, 1024, 0, stream>>>(deg, incl, bsum);
  scan2_kernel<<<1, 64, 0, stream>>>(bsum, nblk);
  scan3_kernel<<<nblk, 1024, 0, stream>>>(incl, deg, bsum, rowptr, cursor, nblk);
  scatter_kernel<<<(EE+255)/256, 256, 0, stream>>>(ei, cursor, sedata);

  node_attn_kernel<<<(NN+1)/2, 128, 0, stream>>>(sedata, nuv, xl, xr, We, att,
                                                 cbias, gamma, beta,
                                                 rowptr, identity,
                                                 alpha_out, denomb, hbuf);
  alpha_fin_kernel<<<(EE+255)/256, 256, 0, stream>>>(ei, denomb, alpha_out);

  dim3 g1(2, NPAD/128);
  mfma_gemm_kernel<<<g1, 256, 0, stream>>>(hbuf, wtp, bp, out, nullptr, nullptr, NN, HIDC);
}